// Round 9
// baseline (661.928 us; speedup 1.0000x reference)
//
#include <hip/hip_runtime.h>
#include <math.h>

#define B_ 16
#define C_ 129
#define T_ 2000
#define NF_ 40
#define ED_ 64
#define K_ 16
#define TP_ 500

// workspace float offsets
#define OFF_SB2 1040     // 40     folded sconv bias
#define OFF_PWC 1088     // 3200   pw weights * pbn scale
#define OFF_PB2 4288     // 80     folded pw bias
#define OFF_WP  4368     // 1280   wx0 @ proj_w  (16x80)
#define OFF_BP  5648     // 16     wx0 @ proj_b + b0
#define OFF_M0  5664     // 256    L0@L0.T - exp(ll0) I
#define OFF_M1  5920     // 256    L1@L1.T - exp(ll1) I
#define OFF_W1A 6224     // 768    tconv A-frag prepack (3 mt x 64 lanes x 8 bf16)
#define OFF_W2U 8192     // bf16 A-frag prepack of sconv weights: 396288 ushort
#define OFF_XP  1495040  // 16*500*16  per-step cell0 input projection
#define OFF_S2R 1623040  // 1.28M  raw sconv accumulator (atomicAdd target)

typedef __attribute__((ext_vector_type(8))) short s8v;
typedef __attribute__((ext_vector_type(4))) float f4v;

#define XROW 292         // xs row stride: 256 t + 24 halo + 12 left pad

__device__ __forceinline__ float elu_f(float x) {
    return x > 0.f ? x : (__expf(x) - 1.f);
}
// tanh(x) given a2 = 2x: 1 - 2*rcp(e^{2x}+1); saturates correctly at +-inf
__device__ __forceinline__ float tanh2_f(float a2) {
    return fmaf(-2.f, __builtin_amdgcn_rcpf(__expf(a2) + 1.f), 1.f);
}
// round-half-up fp32 -> bf16
__device__ __forceinline__ unsigned bfr(float v) {
    return (__float_as_uint(v) + 0x8000u) >> 16;
}

// DPP helpers (k3): row_ror:n ctrl = 0x120+n, rows of 16 lanes.
#define DPPF(v, ctrl) __int_as_float(__builtin_amdgcn_update_dpp( \
    0, __float_as_int(v), (ctrl), 0xF, 0xF, false))
#define DPPI(v, ctrl) __builtin_amdgcn_update_dpp(0, (v), (ctrl), 0xF, 0xF, false)

#define ALLGATHER16F(dst, src) do {        \
    dst[0] = (src);                        \
    dst[1] = DPPF(dst[0], 0x121);          \
    dst[2] = DPPF(dst[0], 0x122);          \
    dst[3] = DPPF(dst[1], 0x122);          \
    dst[4] = DPPF(dst[0], 0x124);          \
    dst[5] = DPPF(dst[1], 0x124);          \
    dst[6] = DPPF(dst[2], 0x124);          \
    dst[7] = DPPF(dst[3], 0x124);          \
    dst[8] = DPPF(dst[0], 0x128);          \
    dst[9] = DPPF(dst[1], 0x128);          \
    dst[10] = DPPF(dst[2], 0x128);         \
    dst[11] = DPPF(dst[3], 0x128);         \
    dst[12] = DPPF(dst[4], 0x128);         \
    dst[13] = DPPF(dst[5], 0x128);         \
    dst[14] = DPPF(dst[6], 0x128);         \
    dst[15] = DPPF(dst[7], 0x128);         \
} while (0)

#define ALLGATHER16I(dst, src) do {        \
    dst[0] = (src);                        \
    dst[1] = DPPI(dst[0], 0x121);          \
    dst[2] = DPPI(dst[0], 0x122);          \
    dst[3] = DPPI(dst[1], 0x122);          \
    dst[4] = DPPI(dst[0], 0x124);          \
    dst[5] = DPPI(dst[1], 0x124);          \
    dst[6] = DPPI(dst[2], 0x124);          \
    dst[7] = DPPI(dst[3], 0x124);          \
    dst[8] = DPPI(dst[0], 0x128);          \
    dst[9] = DPPI(dst[1], 0x128);          \
    dst[10] = DPPI(dst[2], 0x128);         \
    dst[11] = DPPI(dst[3], 0x128);         \
    dst[12] = DPPI(dst[4], 0x128);         \
    dst[13] = DPPI(dst[5], 0x128);         \
    dst[14] = DPPI(dst[6], 0x128);         \
    dst[15] = DPPI(dst[7], 0x128);         \
} while (0)

#define RSUM16(s) do {                     \
    s += DPPF(s, 0x128);                   \
    s += DPPF(s, 0x124);                   \
    s += DPPF(s, 0x122);                   \
    s += DPPF(s, 0x121);                   \
} while (0)

struct P0 {
    const float *tconv_w, *tconv_b, *tbn_g, *tbn_b, *tbn_m, *tbn_v;
    const float *sconv_b, *sbn_g, *sbn_b, *sbn_m, *sbn_v;
    const float *pw_w, *pw_b, *pbn_g, *pbn_b, *pbn_m, *pbn_v;
    const float *proj_w, *proj_b, *wx0, *b0, *L0, *ll0, *L1, *ll1;
    float* ws;
};

__global__ __launch_bounds__(256) void k0a_setup(P0 p) {
    const int tid = blockIdx.x * 256 + threadIdx.x;
    const int stride = gridDim.x * 256;
    float* ws = p.ws;
    const float eps = 1e-5f;
    // tconv A-frag prepack (bf16): A[m=f][k=tap], K=32; tap 25 = folded bias
    for (int e = tid; e < 192; e += stride) {
        const int mt = e >> 6, L = e & 63;
        const int f = mt * 16 + (L & 15);
        float inv = 0.f, bias = 0.f;
        if (f < NF_) {
            inv = p.tbn_g[f] / sqrtf(p.tbn_v[f] + eps);
            bias = p.tconv_b[f] * inv + p.tbn_b[f] - p.tbn_m[f] * inv;
        }
        unsigned short* dst = ((unsigned short*)(ws + OFF_W1A)) + e * 8;
#pragma unroll
        for (int j = 0; j < 8; ++j) {
            const int k = (L >> 4) * 8 + j;
            float v = 0.f;
            if (f < NF_) {
                if (k < 25) v = p.tconv_w[f * 25 + k] * inv;
                else if (k == 25) v = bias;
            }
            dst[j] = (unsigned short)bfr(v);
        }
    }
    for (int f = tid; f < NF_; f += stride) {
        const float sinv = p.sbn_g[f] / sqrtf(p.sbn_v[f] + eps);
        ws[OFF_SB2 + f] = p.sconv_b[f] * sinv + p.sbn_b[f] - p.sbn_m[f] * sinv;
    }
    for (int e = tid; e < 3200; e += stride) {
        const int g = e / 40;
        const float pinv = p.pbn_g[g] / sqrtf(p.pbn_v[g] + eps);
        ws[OFF_PWC + e] = p.pw_w[e] * pinv;
    }
    for (int g = tid; g < 80; g += stride) {
        const float pinv = p.pbn_g[g] / sqrtf(p.pbn_v[g] + eps);
        ws[OFF_PB2 + g] = p.pw_b[g] * pinv + p.pbn_b[g] - p.pbn_m[g] * pinv;
    }
    for (int e = tid; e < 1280; e += stride) {
        const int k = e / 80, g = e - k * 80;
        float a = 0.f;
        for (int ee = 0; ee < ED_; ++ee)
            a = fmaf(p.wx0[k * ED_ + ee], p.proj_w[ee * 80 + g], a);
        ws[OFF_WP + e] = a;
    }
    for (int k = tid; k < K_; k += stride) {
        float a = p.b0[k];
        for (int ee = 0; ee < ED_; ++ee)
            a = fmaf(p.wx0[k * ED_ + ee], p.proj_b[ee], a);
        ws[OFF_BP + k] = a;
    }
    for (int e = tid; e < 256; e += stride) {
        const int k = e >> 4, j = e & 15;
        float a0 = 0.f, a1 = 0.f;
        for (int i = 0; i < 16; ++i) {
            a0 = fmaf(p.L0[k * 16 + i], p.L0[j * 16 + i], a0);
            a1 = fmaf(p.L1[k * 16 + i], p.L1[j * 16 + i], a1);
        }
        if (k == j) { a0 -= expf(p.ll0[0]); a1 -= expf(p.ll1[0]); }
        ws[OFF_M0 + e] = a0;
        ws[OFF_M1 + e] = a1;
    }
}

// Prepack sconv weights * sbn scale into bf16 MFMA A-fragment order.
__global__ __launch_bounds__(256) void k0b_repack(
    const float* __restrict__ sconv_w, const float* __restrict__ sbn_g,
    const float* __restrict__ sbn_v, unsigned short* __restrict__ w2b) {
    const int e = blockIdx.x * 256 + threadIdx.x;
    if (e >= C_ * 3 * 2 * 64) return;
    const int c = e / 384;
    int r = e - c * 384;
    const int mt = r >> 7; r &= 127;
    const int kc = r >> 6;
    const int lane = r & 63;
    const int g = mt * 16 + (lane & 15);
    const float sinv = (g < NF_) ? sbn_g[g] * rsqrtf(sbn_v[g] + 1e-5f) : 0.f;
    unsigned short o[8];
#pragma unroll
    for (int j = 0; j < 8; ++j) {
        const int f = kc * 32 + (lane >> 4) * 8 + j;
        float v = 0.f;
        if (g < NF_ && f < NF_) v = sconv_w[g * (NF_ * C_) + f * C_ + c] * sinv;
        o[j] = (unsigned short)bfr(v);
    }
    unsigned short* dst = w2b + (size_t)e * 8;
#pragma unroll
    for (int j = 0; j < 8; ++j) dst[j] = o[j];
}

// zero the raw accumulator (ws is re-poisoned 0xAA before every launch)
__global__ __launch_bounds__(256) void k1z(float4* __restrict__ p) {
    const int i = blockIdx.x * 256 + threadIdx.x;
    if (i < 320000) p[i] = make_float4(0.f, 0.f, 0.f, 0.f);
}

// Both convs on MFMA (round-7 verified, unchanged).
__global__ __launch_bounds__(256, 3) void k1_mfma(
    const float* __restrict__ x, const unsigned short* __restrict__ w1a,
    const unsigned short* __restrict__ w2b, float* __restrict__ s2raw) {
    __shared__ float xs[17 * XROW];
    __shared__ unsigned int vsI[8192];

    const int tid = threadIdx.x;
    const int split = blockIdx.x & 7;
    const int tile = (blockIdx.x >> 3) & 7;
    const int b = blockIdx.x >> 6;
    const int c0 = (split * C_) >> 3;
    const int c1 = ((split + 1) * C_) >> 3;
    const int cc = c1 - c0;
    const int t0 = tile << 8;
    const int w = tid >> 6;
    const int lane = tid & 63;
    const int n = lane & 15;
    const int q = lane >> 4;
    const int qh = q >> 1;
    const int q1_2 = (q & 1) * 2;
    const bool q3 = (q == 3);
    const int wb = w << 11;
    const int w64 = w << 6;
    const int ln8 = n + q * 8;

    for (int i = tid; i < 8192; i += 256) vsI[i] = 0u;
    for (int e = tid; e < cc * XROW; e += 256) {
        const int cl = e / XROW;
        const int i = e - cl * XROW;
        const int t = t0 - 12 + i;
        float v = 0.f;
        if ((unsigned)t < (unsigned)T_) v = x[(b * C_ + c0 + cl) * T_ + t];
        xs[e] = v;
    }
    __syncthreads();

    const s8v* w1a8 = (const s8v*)w1a;
    s8v wA[3];
#pragma unroll
    for (int mt = 0; mt < 3; ++mt) wA[mt] = w1a8[mt * 64 + lane];

    f4v acc[4][3];
#pragma unroll
    for (int nt = 0; nt < 4; ++nt)
#pragma unroll
        for (int mt = 0; mt < 3; ++mt) acc[nt][mt] = (f4v)0.f;

    const s8v* w2b8 = (const s8v*)w2b;
    const f4v z4 = (f4v)0.f;

    for (int cl = 0; cl < cc; ++cl) {
        const int c = c0 + cl;
        s8v af[3][2];
#pragma unroll
        for (int mt = 0; mt < 3; ++mt)
#pragma unroll
            for (int kc = 0; kc < 2; ++kc)
                af[mt][kc] = w2b8[((c * 3 + mt) * 2 + kc) * 64 + lane];

        const float* xrow = &xs[cl * XROW + w64 + ln8];

#pragma unroll
        for (int nt = 0; nt < 4; ++nt) {
            float bx[8];
#pragma unroll
            for (int j = 0; j < 8; ++j) bx[j] = xrow[nt * 16 + j];
            if (q3) bx[1] = 1.0f;
            unsigned pw_[4];
#pragma unroll
            for (int jj = 0; jj < 4; ++jj)
                pw_[jj] = bfr(bx[2 * jj]) |
                    ((__float_as_uint(bx[2 * jj + 1]) + 0x8000u) & 0xFFFF0000u);
            const s8v bh = *(const s8v*)pw_;
#pragma unroll
            for (int mt = 0; mt < 3; ++mt) {
                const f4v vT = __builtin_amdgcn_mfma_f32_16x16x32_bf16(
                    wA[mt], bh, z4, 0, 0, 0);
                const float e0 = elu_f(vT[0]);
                const float e1 = elu_f(vT[1]);
                const float e2 = elu_f(vT[2]);
                const float e3 = elu_f(vT[3]);
                const unsigned lo = bfr(e0) |
                    ((__float_as_uint(e1) + 0x8000u) & 0xFFFF0000u);
                const unsigned hi = bfr(e2) |
                    ((__float_as_uint(e3) + 0x8000u) & 0xFFFF0000u);
                const int base = wb + ((nt * 8 + 2 * mt + qh) << 6) + (n << 2) + q1_2;
                vsI[base] = lo;
                vsI[base + 1] = hi;
            }
        }
        __builtin_amdgcn_wave_barrier();

#pragma unroll
        for (int nt = 0; nt < 4; ++nt) {
            const s8v b0 = *(const s8v*)&vsI[wb + ((nt * 8 + q) << 6) + (n << 2)];
            const s8v b1 = *(const s8v*)&vsI[wb + ((nt * 8 + 4 + q) << 6) + (n << 2)];
#pragma unroll
            for (int mt = 0; mt < 3; ++mt) {
                acc[nt][mt] = __builtin_amdgcn_mfma_f32_16x16x32_bf16(
                    af[mt][0], b0, acc[nt][mt], 0, 0, 0);
                acc[nt][mt] = __builtin_amdgcn_mfma_f32_16x16x32_bf16(
                    af[mt][1], b1, acc[nt][mt], 0, 0, 0);
            }
        }
        __builtin_amdgcn_wave_barrier();
    }

#pragma unroll
    for (int nt = 0; nt < 4; ++nt) {
        const int t = t0 + w * 64 + nt * 16 + n;
        if (t >= T_) continue;
#pragma unroll
        for (int mt = 0; mt < 3; ++mt) {
#pragma unroll
            for (int r = 0; r < 4; ++r) {
                const int g = mt * 16 + q * 4 + r;
                if (g < NF_)
                    atomicAdd(&s2raw[(b * NF_ + g) * T_ + t], acc[nt][mt][r]);
            }
        }
    }
}

// Fused dw/pw/pool/proj (round-7 verified, unchanged).
__global__ __launch_bounds__(256) void k2_dwpw(
    const float* __restrict__ s2raw, const float* __restrict__ sb2,
    const float* __restrict__ dw_w, const float* __restrict__ dw_b,
    const float* __restrict__ pwc, const float* __restrict__ pb2,
    const float* __restrict__ WP, const float* __restrict__ bp,
    float* __restrict__ xp) {
    __shared__ float st[NF_ * 114];
    __shared__ float dwo[NF_ * 100];
    __shared__ float dwwl[NF_ * 15];
    __shared__ float dwbl[NF_];
    __shared__ float pwcl[80 * 40];
    __shared__ float pb2l[80];
    __shared__ float WPl[K_ * 80];
    __shared__ float bpl[K_];
    __shared__ float po[80 * 25];
    const int tid = threadIdx.x;
    const int b = blockIdx.x / 20;
    const int tp0 = (blockIdx.x % 20) * 25;
    const int tbase = tp0 * 4 - 7;
    for (int e = tid; e < NF_ * 114; e += 256) {
        const int f = e / 114;
        const int i = e - f * 114;
        const int t = tbase + i;
        float v = 0.f;
        if ((unsigned)t < (unsigned)T_)
            v = elu_f(s2raw[(b * NF_ + f) * T_ + t] + sb2[f]);
        st[e] = v;
    }
    for (int e = tid; e < 600; e += 256) dwwl[e] = dw_w[e];
    for (int e = tid; e < 3200; e += 256) pwcl[e] = pwc[e];
    for (int e = tid; e < 1280; e += 256) WPl[e] = WP[e];
    if (tid < NF_) dwbl[tid] = dw_b[tid];
    if (tid < 80) pb2l[tid] = pb2[tid];
    if (tid < K_) bpl[tid] = bp[tid];
    __syncthreads();
    for (int e = tid; e < 4000; e += 256) {
        const int f = e / 100;
        const int tq = e - f * 100;
        float a = dwbl[f];
#pragma unroll
        for (int kk = 0; kk < 15; ++kk)
            a = fmaf(dwwl[f * 15 + kk], st[f * 114 + tq + kk], a);
        dwo[e] = a;
    }
    __syncthreads();
    for (int e = tid; e < 2000; e += 256) {
        const int g = e / 25;
        const int tp = e - g * 25;
        float sum = 0.f;
#pragma unroll
        for (int dt = 0; dt < 4; ++dt) {
            float a = pb2l[g];
            for (int f = 0; f < NF_; ++f)
                a = fmaf(pwcl[g * 40 + f], dwo[f * 100 + tp * 4 + dt], a);
            sum += elu_f(a);
        }
        po[e] = sum * 0.25f;
    }
    __syncthreads();
    for (int e = tid; e < 400; e += 256) {
        const int tp = e >> 4;
        const int k = e & 15;
        float a = bpl[k];
        for (int g = 0; g < 80; ++g)
            a = fmaf(WPl[k * 80 + g], po[g * 25 + tp], a);
        xp[(b * TP_ + tp0 + tp) * K_ + k] = a;
    }
}

// Sequential 500-step scan, DPP cross-lane (round-7 logic), now 8 waves in
// ONE block (2 waves/SIMD -> dependent-stall interleave) with 2 batches per
// wave (rows 2,3 mirror rows 0,1); rcp-based tanh with 2x prefolded into LN.
__global__ __launch_bounds__(512, 1) void k3_scan(
    const float* __restrict__ xp, const float* __restrict__ M0,
    const float* __restrict__ M1, const float* __restrict__ wx1,
    const float* __restrict__ b1, const float* __restrict__ ln0_g,
    const float* __restrict__ ln0_b, const float* __restrict__ ln1_g,
    const float* __restrict__ ln1_b, float* __restrict__ out) {
    const int tid = threadIdx.x;
    const int w = tid >> 6;
    const int lane = tid & 63;
    const int row = (lane >> 4) & 1;     // rows 2,3 duplicate rows 0,1
    const int b = w * 2 + row;
    const int k = lane & 15;

    int pidx[16];
    ALLGATHER16I(pidx, k);

    float M0r[16], M1r[16], w1r[16];
#pragma unroll
    for (int j = 0; j < 16; ++j) {
        M0r[j] = M0[k * 16 + pidx[j]];
        M1r[j] = M1[k * 16 + pidx[j]];
        w1r[j] = wx1[k * 16 + pidx[j]];
    }
    const float b1r = b1[k];
    const float g0 = 2.f * ln0_g[k], be0 = 2.f * ln0_b[k];
    const float g1 = 2.f * ln1_g[k], be1 = 2.f * ln1_b[k];
    const float* xpb = xp + b * TP_ * K_ + k;

    // prologue: h0_0 = tanh(LN(x_0))  (matvec term vanishes at h0=0)
    float x0 = xpb[0];
    {
        float s1 = x0, s2 = x0 * x0;
        RSUM16(s1);
        RSUM16(s2);
        const float mu = s1 * 0.0625f;
        const float var = s2 * 0.0625f - mu * mu;
        const float r = rsqrtf(var + 1e-5f);
        x0 = tanh2_f(fmaf((x0 - mu) * r, g0, be0));
    }
    float h0c = x0;   // h0 at step t
    float h1c = 0.f;  // h1 at step t-1

    float xn[4];
    xn[1] = xpb[1 * K_];
    xn[2] = xpb[2 * K_];
    xn[3] = xpb[3 * K_];
    xn[0] = xpb[4 * K_];

    for (int t = 0; t < TP_; ++t) {
        float h0g[16], h1g[16];
        ALLGATHER16F(h0g, h0c);
        ALLGATHER16F(h1g, h1c);
        const int slot = (t + 1) & 3;
        const float xv = xn[slot];
        int tf = t + 5;
        if (tf > TP_ - 1) tf = TP_ - 1;
        xn[slot] = xpb[tf * K_];

        // chain B: cell1 at step t
        float q0 = b1r, q1 = 0.f, q2 = 0.f, q3 = 0.f;
#pragma unroll
        for (int j = 0; j < 16; j += 4) {
            q0 = fmaf(w1r[j],     h0g[j],     q0);
            q1 = fmaf(w1r[j + 1], h0g[j + 1], q1);
            q2 = fmaf(w1r[j + 2], h0g[j + 2], q2);
            q3 = fmaf(w1r[j + 3], h0g[j + 3], q3);
        }
#pragma unroll
        for (int j = 0; j < 16; j += 4) {
            q0 = fmaf(M1r[j],     h1g[j],     q0);
            q1 = fmaf(M1r[j + 1], h1g[j + 1], q1);
            q2 = fmaf(M1r[j + 2], h1g[j + 2], q2);
            q3 = fmaf(M1r[j + 3], h1g[j + 3], q3);
        }
        const float pre1 = (q0 + q1) + (q2 + q3);
        float u1 = pre1, u2 = pre1 * pre1;
        RSUM16(u1);
        RSUM16(u2);
        const float mu1 = u1 * 0.0625f;
        const float var1 = u2 * 0.0625f - mu1 * mu1;
        const float r1 = rsqrtf(var1 + 1e-5f);
        const float h1n = tanh2_f(fmaf((pre1 - mu1) * r1, g1, be1));

        // chain A: cell0 at step t+1
        float p0 = xv, p1 = 0.f, p2 = 0.f, p3 = 0.f;
#pragma unroll
        for (int j = 0; j < 16; j += 4) {
            p0 = fmaf(M0r[j],     h0g[j],     p0);
            p1 = fmaf(M0r[j + 1], h0g[j + 1], p1);
            p2 = fmaf(M0r[j + 2], h0g[j + 2], p2);
            p3 = fmaf(M0r[j + 3], h0g[j + 3], p3);
        }
        const float pre0 = (p0 + p1) + (p2 + p3);
        float s1 = pre0, s2 = pre0 * pre0;
        RSUM16(s1);
        RSUM16(s2);
        const float mu0 = s1 * 0.0625f;
        const float var0 = s2 * 0.0625f - mu0 * mu0;
        const float r0 = rsqrtf(var0 + 1e-5f);
        const float h0n = tanh2_f(fmaf((pre0 - mu0) * r0, g0, be0));

        h1c = h1n;
        h0c = h0n;
    }
    if (lane < 32) {
        out[b * K_ + k] = h1c;              // Z
        if (k == 0) out[256 + b] = 1.0f;    // alpha = softmax over size-1 axis
    }
}

extern "C" void kernel_launch(void* const* d_in, const int* in_sizes, int n_in,
                              void* d_out, int out_size, void* d_ws, size_t ws_size,
                              hipStream_t stream) {
    const float* x       = (const float*)d_in[0];
    const float* sconv_w = (const float*)d_in[7];
    const float* sbn_g   = (const float*)d_in[9];
    const float* sbn_v   = (const float*)d_in[12];
    const float* dw_w    = (const float*)d_in[13];
    const float* dw_b    = (const float*)d_in[14];
    const float* wx1     = (const float*)d_in[29];
    const float* b1      = (const float*)d_in[32];
    const float* ln0_g   = (const float*)d_in[27];
    const float* ln0_b   = (const float*)d_in[28];
    const float* ln1_g   = (const float*)d_in[33];
    const float* ln1_b   = (const float*)d_in[34];
    float* ws = (float*)d_ws;
    float* out = (float*)d_out;

    P0 p;
    p.tconv_w = (const float*)d_in[1]; p.tconv_b = (const float*)d_in[2];
    p.tbn_g = (const float*)d_in[3]; p.tbn_b = (const float*)d_in[4];
    p.tbn_m = (const float*)d_in[5]; p.tbn_v = (const float*)d_in[6];
    p.sconv_b = (const float*)d_in[8];
    p.sbn_g = sbn_g; p.sbn_b = (const float*)d_in[10];
    p.sbn_m = (const float*)d_in[11]; p.sbn_v = sbn_v;
    p.pw_w = (const float*)d_in[15]; p.pw_b = (const float*)d_in[16];
    p.pbn_g = (const float*)d_in[17]; p.pbn_b = (const float*)d_in[18];
    p.pbn_m = (const float*)d_in[19]; p.pbn_v = (const float*)d_in[20];
    p.proj_w = (const float*)d_in[21]; p.proj_b = (const float*)d_in[22];
    p.wx0 = (const float*)d_in[23]; p.b0 = (const float*)d_in[26];
    p.L0 = (const float*)d_in[24]; p.ll0 = (const float*)d_in[25];
    p.L1 = (const float*)d_in[30]; p.ll1 = (const float*)d_in[31];
    p.ws = ws;

    unsigned short* w2b = (unsigned short*)(ws + OFF_W2U);
    unsigned short* w1a = (unsigned short*)(ws + OFF_W1A);

    k0a_setup<<<dim3(8), dim3(256), 0, stream>>>(p);
    k0b_repack<<<dim3(194), dim3(256), 0, stream>>>(sconv_w, sbn_g, sbn_v, w2b);
    k1z<<<dim3(1250), dim3(256), 0, stream>>>((float4*)(ws + OFF_S2R));
    k1_mfma<<<dim3(1024), dim3(256), 0, stream>>>(x, w1a, w2b, ws + OFF_S2R);
    k2_dwpw<<<dim3(320), dim3(256), 0, stream>>>(ws + OFF_S2R, ws + OFF_SB2,
                                                 dw_w, dw_b, ws + OFF_PWC,
                                                 ws + OFF_PB2, ws + OFF_WP, ws + OFF_BP,
                                                 ws + OFF_XP);
    k3_scan<<<dim3(1), dim3(512), 0, stream>>>(ws + OFF_XP, ws + OFF_M0, ws + OFF_M1,
                                               wx1, b1, ln0_g, ln0_b, ln1_g, ln1_b, out);
}

// Round 10
// 466.211 us; speedup vs baseline: 1.4198x; 1.4198x over previous
//
#include <hip/hip_runtime.h>
#include <math.h>

#define B_ 16
#define C_ 129
#define T_ 2000
#define NF_ 40
#define ED_ 64
#define K_ 16
#define TP_ 500

// workspace float offsets
#define OFF_SB2 1040     // 40     folded sconv bias
#define OFF_PWC 1088     // 3200   pw weights * pbn scale
#define OFF_PB2 4288     // 80     folded pw bias
#define OFF_WP  4368     // 1280   wx0 @ proj_w  (16x80)
#define OFF_BP  5648     // 16     wx0 @ proj_b + b0
#define OFF_M0  5664     // 256    L0@L0.T - exp(ll0) I
#define OFF_M1  5920     // 256    L1@L1.T - exp(ll1) I
#define OFF_W1A 6224     // 768    tconv A-frag prepack (3 mt x 64 lanes x 8 bf16)
#define OFF_W2U 8192     // bf16 A-frag prepack of sconv weights: 396288 ushort
#define OFF_XP  1495040  // 16*500*16  per-step cell0 input projection
#define OFF_S2R 1623040  // 1.28M  raw sconv accumulator (atomicAdd target)

typedef __attribute__((ext_vector_type(8))) short s8v;
typedef __attribute__((ext_vector_type(4))) float f4v;

#define XROW 292         // xs row stride: 256 t + 24 halo + 12 left pad

__device__ __forceinline__ float elu_f(float x) {
    return x > 0.f ? x : (__expf(x) - 1.f);
}
// tanh(x) given a2 = 2x: 1 - 2*rcp(e^{2x}+1); saturates correctly at +-inf
__device__ __forceinline__ float tanh2_f(float a2) {
    return fmaf(-2.f, __builtin_amdgcn_rcpf(__expf(a2) + 1.f), 1.f);
}
// round-half-up fp32 -> bf16
__device__ __forceinline__ unsigned bfr(float v) {
    return (__float_as_uint(v) + 0x8000u) >> 16;
}

// DPP helpers (k3): row_ror:n ctrl = 0x120+n, rows of 16 lanes.
#define DPPF(v, ctrl) __int_as_float(__builtin_amdgcn_update_dpp( \
    0, __float_as_int(v), (ctrl), 0xF, 0xF, false))
#define DPPI(v, ctrl) __builtin_amdgcn_update_dpp(0, (v), (ctrl), 0xF, 0xF, false)

#define ALLGATHER16F(dst, src) do {        \
    dst[0] = (src);                        \
    dst[1] = DPPF(dst[0], 0x121);          \
    dst[2] = DPPF(dst[0], 0x122);          \
    dst[3] = DPPF(dst[1], 0x122);          \
    dst[4] = DPPF(dst[0], 0x124);          \
    dst[5] = DPPF(dst[1], 0x124);          \
    dst[6] = DPPF(dst[2], 0x124);          \
    dst[7] = DPPF(dst[3], 0x124);          \
    dst[8] = DPPF(dst[0], 0x128);          \
    dst[9] = DPPF(dst[1], 0x128);          \
    dst[10] = DPPF(dst[2], 0x128);         \
    dst[11] = DPPF(dst[3], 0x128);         \
    dst[12] = DPPF(dst[4], 0x128);         \
    dst[13] = DPPF(dst[5], 0x128);         \
    dst[14] = DPPF(dst[6], 0x128);         \
    dst[15] = DPPF(dst[7], 0x128);         \
} while (0)

#define ALLGATHER16I(dst, src) do {        \
    dst[0] = (src);                        \
    dst[1] = DPPI(dst[0], 0x121);          \
    dst[2] = DPPI(dst[0], 0x122);          \
    dst[3] = DPPI(dst[1], 0x122);          \
    dst[4] = DPPI(dst[0], 0x124);          \
    dst[5] = DPPI(dst[1], 0x124);          \
    dst[6] = DPPI(dst[2], 0x124);          \
    dst[7] = DPPI(dst[3], 0x124);          \
    dst[8] = DPPI(dst[0], 0x128);          \
    dst[9] = DPPI(dst[1], 0x128);          \
    dst[10] = DPPI(dst[2], 0x128);         \
    dst[11] = DPPI(dst[3], 0x128);         \
    dst[12] = DPPI(dst[4], 0x128);         \
    dst[13] = DPPI(dst[5], 0x128);         \
    dst[14] = DPPI(dst[6], 0x128);         \
    dst[15] = DPPI(dst[7], 0x128);         \
} while (0)

#define RSUM16(s) do {                     \
    s += DPPF(s, 0x128);                   \
    s += DPPF(s, 0x124);                   \
    s += DPPF(s, 0x122);                   \
    s += DPPF(s, 0x121);                   \
} while (0)

struct P0 {
    const float *tconv_w, *tconv_b, *tbn_g, *tbn_b, *tbn_m, *tbn_v;
    const float *sconv_b, *sbn_g, *sbn_b, *sbn_m, *sbn_v;
    const float *pw_w, *pw_b, *pbn_g, *pbn_b, *pbn_m, *pbn_v;
    const float *proj_w, *proj_b, *wx0, *b0, *L0, *ll0, *L1, *ll1;
    float* ws;
};

__global__ __launch_bounds__(256) void k0a_setup(P0 p) {
    const int tid = blockIdx.x * 256 + threadIdx.x;
    const int stride = gridDim.x * 256;
    float* ws = p.ws;
    const float eps = 1e-5f;
    // tconv A-frag prepack (bf16): A[m=f][k=tap], K=32; tap 25 = folded bias
    for (int e = tid; e < 192; e += stride) {
        const int mt = e >> 6, L = e & 63;
        const int f = mt * 16 + (L & 15);
        float inv = 0.f, bias = 0.f;
        if (f < NF_) {
            inv = p.tbn_g[f] / sqrtf(p.tbn_v[f] + eps);
            bias = p.tconv_b[f] * inv + p.tbn_b[f] - p.tbn_m[f] * inv;
        }
        unsigned short* dst = ((unsigned short*)(ws + OFF_W1A)) + e * 8;
#pragma unroll
        for (int j = 0; j < 8; ++j) {
            const int k = (L >> 4) * 8 + j;
            float v = 0.f;
            if (f < NF_) {
                if (k < 25) v = p.tconv_w[f * 25 + k] * inv;
                else if (k == 25) v = bias;
            }
            dst[j] = (unsigned short)bfr(v);
        }
    }
    for (int f = tid; f < NF_; f += stride) {
        const float sinv = p.sbn_g[f] / sqrtf(p.sbn_v[f] + eps);
        ws[OFF_SB2 + f] = p.sconv_b[f] * sinv + p.sbn_b[f] - p.sbn_m[f] * sinv;
    }
    for (int e = tid; e < 3200; e += stride) {
        const int g = e / 40;
        const float pinv = p.pbn_g[g] / sqrtf(p.pbn_v[g] + eps);
        ws[OFF_PWC + e] = p.pw_w[e] * pinv;
    }
    for (int g = tid; g < 80; g += stride) {
        const float pinv = p.pbn_g[g] / sqrtf(p.pbn_v[g] + eps);
        ws[OFF_PB2 + g] = p.pw_b[g] * pinv + p.pbn_b[g] - p.pbn_m[g] * pinv;
    }
    for (int e = tid; e < 1280; e += stride) {
        const int k = e / 80, g = e - k * 80;
        float a = 0.f;
        for (int ee = 0; ee < ED_; ++ee)
            a = fmaf(p.wx0[k * ED_ + ee], p.proj_w[ee * 80 + g], a);
        ws[OFF_WP + e] = a;
    }
    for (int k = tid; k < K_; k += stride) {
        float a = p.b0[k];
        for (int ee = 0; ee < ED_; ++ee)
            a = fmaf(p.wx0[k * ED_ + ee], p.proj_b[ee], a);
        ws[OFF_BP + k] = a;
    }
    for (int e = tid; e < 256; e += stride) {
        const int k = e >> 4, j = e & 15;
        float a0 = 0.f, a1 = 0.f;
        for (int i = 0; i < 16; ++i) {
            a0 = fmaf(p.L0[k * 16 + i], p.L0[j * 16 + i], a0);
            a1 = fmaf(p.L1[k * 16 + i], p.L1[j * 16 + i], a1);
        }
        if (k == j) { a0 -= expf(p.ll0[0]); a1 -= expf(p.ll1[0]); }
        ws[OFF_M0 + e] = a0;
        ws[OFF_M1 + e] = a1;
    }
}

// Prepack sconv weights * sbn scale into bf16 MFMA A-fragment order.
__global__ __launch_bounds__(256) void k0b_repack(
    const float* __restrict__ sconv_w, const float* __restrict__ sbn_g,
    const float* __restrict__ sbn_v, unsigned short* __restrict__ w2b) {
    const int e = blockIdx.x * 256 + threadIdx.x;
    if (e >= C_ * 3 * 2 * 64) return;
    const int c = e / 384;
    int r = e - c * 384;
    const int mt = r >> 7; r &= 127;
    const int kc = r >> 6;
    const int lane = r & 63;
    const int g = mt * 16 + (lane & 15);
    const float sinv = (g < NF_) ? sbn_g[g] * rsqrtf(sbn_v[g] + 1e-5f) : 0.f;
    unsigned short o[8];
#pragma unroll
    for (int j = 0; j < 8; ++j) {
        const int f = kc * 32 + (lane >> 4) * 8 + j;
        float v = 0.f;
        if (g < NF_ && f < NF_) v = sconv_w[g * (NF_ * C_) + f * C_ + c] * sinv;
        o[j] = (unsigned short)bfr(v);
    }
    unsigned short* dst = w2b + (size_t)e * 8;
#pragma unroll
    for (int j = 0; j < 8; ++j) dst[j] = o[j];
}

// zero the raw accumulator (ws is re-poisoned 0xAA before every launch)
__global__ __launch_bounds__(256) void k1z(float4* __restrict__ p) {
    const int i = blockIdx.x * 256 + threadIdx.x;
    if (i < 320000) p[i] = make_float4(0.f, 0.f, 0.f, 0.f);
}

// Both convs on MFMA. Per-nt produce->consume V panel: vsI shrinks 32->8 KB,
// total LDS 28 KB -> 4 blocks/CU resident (grid = 1024 exactly), 16 waves/CU.
// Wave-private panel + in-order DS pipe => still zero __syncthreads in c-loop.
__global__ __launch_bounds__(256, 4) void k1_mfma(
    const float* __restrict__ x, const unsigned short* __restrict__ w1a,
    const unsigned short* __restrict__ w2b, float* __restrict__ s2raw) {
    __shared__ float xs[17 * XROW];
    __shared__ unsigned int vsI[2048];      // 4 waves x 8 rows x 64 words

    const int tid = threadIdx.x;
    const int split = blockIdx.x & 7;
    const int tile = (blockIdx.x >> 3) & 7;
    const int b = blockIdx.x >> 6;
    const int c0 = (split * C_) >> 3;
    const int c1 = ((split + 1) * C_) >> 3;
    const int cc = c1 - c0;
    const int t0 = tile << 8;
    const int w = tid >> 6;
    const int lane = tid & 63;
    const int n = lane & 15;
    const int q = lane >> 4;
    const int qh = q >> 1;
    const int q1_2 = (q & 1) * 2;
    const bool q3 = (q == 3);
    const int wb = w << 9;                  // wave base: 512 words
    const int w64 = w << 6;
    const int ln8 = n + q * 8;

    for (int i = tid; i < 2048; i += 256) vsI[i] = 0u;   // rows 6,7 stay pad-zero
    for (int e = tid; e < cc * XROW; e += 256) {
        const int cl = e / XROW;
        const int i = e - cl * XROW;
        const int t = t0 - 12 + i;
        float v = 0.f;
        if ((unsigned)t < (unsigned)T_) v = x[(b * C_ + c0 + cl) * T_ + t];
        xs[e] = v;
    }
    __syncthreads();

    const s8v* w1a8 = (const s8v*)w1a;
    s8v wA[3];
#pragma unroll
    for (int mt = 0; mt < 3; ++mt) wA[mt] = w1a8[mt * 64 + lane];

    f4v acc[4][3];
#pragma unroll
    for (int nt = 0; nt < 4; ++nt)
#pragma unroll
        for (int mt = 0; mt < 3; ++mt) acc[nt][mt] = (f4v)0.f;

    const s8v* w2b8 = (const s8v*)w2b;
    const f4v z4 = (f4v)0.f;

    for (int cl = 0; cl < cc; ++cl) {
        const int c = c0 + cl;
        s8v af[3][2];
#pragma unroll
        for (int mt = 0; mt < 3; ++mt)
#pragma unroll
            for (int kc = 0; kc < 2; ++kc)
                af[mt][kc] = w2b8[((c * 3 + mt) * 2 + kc) * 64 + lane];

        const float* xrow = &xs[cl * XROW + w64 + ln8];

#pragma unroll
        for (int nt = 0; nt < 4; ++nt) {
            // tconv B-frag (Hankel of x) for this t-subtile
            float bx[8];
#pragma unroll
            for (int j = 0; j < 8; ++j) bx[j] = xrow[nt * 16 + j];
            if (q3) bx[1] = 1.0f;           // k=25: bias channel
            unsigned pw_[4];
#pragma unroll
            for (int jj = 0; jj < 4; ++jj)
                pw_[jj] = bfr(bx[2 * jj]) |
                    ((__float_as_uint(bx[2 * jj + 1]) + 0x8000u) & 0xFFFF0000u);
            const s8v bh = *(const s8v*)pw_;
            // tconv MFMA -> ELU -> pack -> per-nt V panel (rows 0..5; 6,7 pad)
#pragma unroll
            for (int mt = 0; mt < 3; ++mt) {
                const f4v vT = __builtin_amdgcn_mfma_f32_16x16x32_bf16(
                    wA[mt], bh, z4, 0, 0, 0);
                const float e0 = elu_f(vT[0]);
                const float e1 = elu_f(vT[1]);
                const float e2 = elu_f(vT[2]);
                const float e3 = elu_f(vT[3]);
                const unsigned lo = bfr(e0) |
                    ((__float_as_uint(e1) + 0x8000u) & 0xFFFF0000u);
                const unsigned hi = bfr(e2) |
                    ((__float_as_uint(e3) + 0x8000u) & 0xFFFF0000u);
                const int base = wb + ((2 * mt + qh) << 6) + (n << 2) + q1_2;
                vsI[base] = lo;
                vsI[base + 1] = hi;
            }
            __builtin_amdgcn_wave_barrier();
            // sconv MFMA for this t-subtile
            const s8v b0 = *(const s8v*)&vsI[wb + (q << 6) + (n << 2)];
            const s8v b1 = *(const s8v*)&vsI[wb + ((4 + q) << 6) + (n << 2)];
#pragma unroll
            for (int mt = 0; mt < 3; ++mt) {
                acc[nt][mt] = __builtin_amdgcn_mfma_f32_16x16x32_bf16(
                    af[mt][0], b0, acc[nt][mt], 0, 0, 0);
                acc[nt][mt] = __builtin_amdgcn_mfma_f32_16x16x32_bf16(
                    af[mt][1], b1, acc[nt][mt], 0, 0, 0);
            }
            __builtin_amdgcn_wave_barrier();
        }
    }

    // epilogue: C/D layout col=lane&15 (t), row=quad*4+reg (g)
#pragma unroll
    for (int nt = 0; nt < 4; ++nt) {
        const int t = t0 + w * 64 + nt * 16 + n;
        if (t >= T_) continue;
#pragma unroll
        for (int mt = 0; mt < 3; ++mt) {
#pragma unroll
            for (int r = 0; r < 4; ++r) {
                const int g = mt * 16 + q * 4 + r;
                if (g < NF_)
                    atomicAdd(&s2raw[(b * NF_ + g) * T_ + t], acc[nt][mt][r]);
            }
        }
    }
}

// Fused dw/pw/pool/proj (verified, unchanged).
__global__ __launch_bounds__(256) void k2_dwpw(
    const float* __restrict__ s2raw, const float* __restrict__ sb2,
    const float* __restrict__ dw_w, const float* __restrict__ dw_b,
    const float* __restrict__ pwc, const float* __restrict__ pb2,
    const float* __restrict__ WP, const float* __restrict__ bp,
    float* __restrict__ xp) {
    __shared__ float st[NF_ * 114];
    __shared__ float dwo[NF_ * 100];
    __shared__ float dwwl[NF_ * 15];
    __shared__ float dwbl[NF_];
    __shared__ float pwcl[80 * 40];
    __shared__ float pb2l[80];
    __shared__ float WPl[K_ * 80];
    __shared__ float bpl[K_];
    __shared__ float po[80 * 25];
    const int tid = threadIdx.x;
    const int b = blockIdx.x / 20;
    const int tp0 = (blockIdx.x % 20) * 25;
    const int tbase = tp0 * 4 - 7;
    for (int e = tid; e < NF_ * 114; e += 256) {
        const int f = e / 114;
        const int i = e - f * 114;
        const int t = tbase + i;
        float v = 0.f;
        if ((unsigned)t < (unsigned)T_)
            v = elu_f(s2raw[(b * NF_ + f) * T_ + t] + sb2[f]);
        st[e] = v;
    }
    for (int e = tid; e < 600; e += 256) dwwl[e] = dw_w[e];
    for (int e = tid; e < 3200; e += 256) pwcl[e] = pwc[e];
    for (int e = tid; e < 1280; e += 256) WPl[e] = WP[e];
    if (tid < NF_) dwbl[tid] = dw_b[tid];
    if (tid < 80) pb2l[tid] = pb2[tid];
    if (tid < K_) bpl[tid] = bp[tid];
    __syncthreads();
    for (int e = tid; e < 4000; e += 256) {
        const int f = e / 100;
        const int tq = e - f * 100;
        float a = dwbl[f];
#pragma unroll
        for (int kk = 0; kk < 15; ++kk)
            a = fmaf(dwwl[f * 15 + kk], st[f * 114 + tq + kk], a);
        dwo[e] = a;
    }
    __syncthreads();
    for (int e = tid; e < 2000; e += 256) {
        const int g = e / 25;
        const int tp = e - g * 25;
        float sum = 0.f;
#pragma unroll
        for (int dt = 0; dt < 4; ++dt) {
            float a = pb2l[g];
            for (int f = 0; f < NF_; ++f)
                a = fmaf(pwcl[g * 40 + f], dwo[f * 100 + tp * 4 + dt], a);
            sum += elu_f(a);
        }
        po[e] = sum * 0.25f;
    }
    __syncthreads();
    for (int e = tid; e < 400; e += 256) {
        const int tp = e >> 4;
        const int k = e & 15;
        float a = bpl[k];
        for (int g = 0; g < 80; ++g)
            a = fmaf(WPl[k * 80 + g], po[g * 25 + tp], a);
        xp[(b * TP_ + tp0 + tp) * K_ + k] = a;
    }
}

// Sequential 500-step scan: round-7 structure (4 blocks x 1 wave, 4 batches
// per wave — issue-bound per wave, so keep 1 wave/SIMD) + rcp-based tanh
// with the 2x prefolded into LN gamma/beta (removes the precise-div sequence).
__global__ __launch_bounds__(64, 1) void k3_scan(
    const float* __restrict__ xp, const float* __restrict__ M0,
    const float* __restrict__ M1, const float* __restrict__ wx1,
    const float* __restrict__ b1, const float* __restrict__ ln0_g,
    const float* __restrict__ ln0_b, const float* __restrict__ ln1_g,
    const float* __restrict__ ln1_b, float* __restrict__ out) {
    const int lane = threadIdx.x;
    const int b = blockIdx.x * 4 + (lane >> 4);
    const int k = lane & 15;

    int pidx[16];
    ALLGATHER16I(pidx, k);

    float M0r[16], M1r[16], w1r[16];
#pragma unroll
    for (int j = 0; j < 16; ++j) {
        M0r[j] = M0[k * 16 + pidx[j]];
        M1r[j] = M1[k * 16 + pidx[j]];
        w1r[j] = wx1[k * 16 + pidx[j]];
    }
    const float b1r = b1[k];
    const float g0 = 2.f * ln0_g[k], be0 = 2.f * ln0_b[k];
    const float g1 = 2.f * ln1_g[k], be1 = 2.f * ln1_b[k];
    const float* xpb = xp + b * TP_ * K_ + k;

    // prologue: h0_0 = tanh(LN(x_0))  (matvec term vanishes at h0=0)
    float x0 = xpb[0];
    {
        float s1 = x0, s2 = x0 * x0;
        RSUM16(s1);
        RSUM16(s2);
        const float mu = s1 * 0.0625f;
        const float var = s2 * 0.0625f - mu * mu;
        const float r = rsqrtf(var + 1e-5f);
        x0 = tanh2_f(fmaf((x0 - mu) * r, g0, be0));
    }
    float h0c = x0;   // h0 at step t
    float h1c = 0.f;  // h1 at step t-1

    float xn[4];
    xn[1] = xpb[1 * K_];
    xn[2] = xpb[2 * K_];
    xn[3] = xpb[3 * K_];
    xn[0] = xpb[4 * K_];

    for (int t = 0; t < TP_; ++t) {
        float h0g[16], h1g[16];
        ALLGATHER16F(h0g, h0c);
        ALLGATHER16F(h1g, h1c);
        const int slot = (t + 1) & 3;
        const float xv = xn[slot];
        int tf = t + 5;
        if (tf > TP_ - 1) tf = TP_ - 1;
        xn[slot] = xpb[tf * K_];

        // chain B: cell1 at step t
        float q0 = b1r, q1 = 0.f, q2 = 0.f, q3 = 0.f;
#pragma unroll
        for (int j = 0; j < 16; j += 4) {
            q0 = fmaf(w1r[j],     h0g[j],     q0);
            q1 = fmaf(w1r[j + 1], h0g[j + 1], q1);
            q2 = fmaf(w1r[j + 2], h0g[j + 2], q2);
            q3 = fmaf(w1r[j + 3], h0g[j + 3], q3);
        }
#pragma unroll
        for (int j = 0; j < 16; j += 4) {
            q0 = fmaf(M1r[j],     h1g[j],     q0);
            q1 = fmaf(M1r[j + 1], h1g[j + 1], q1);
            q2 = fmaf(M1r[j + 2], h1g[j + 2], q2);
            q3 = fmaf(M1r[j + 3], h1g[j + 3], q3);
        }
        const float pre1 = (q0 + q1) + (q2 + q3);
        float u1 = pre1, u2 = pre1 * pre1;
        RSUM16(u1);
        RSUM16(u2);
        const float mu1 = u1 * 0.0625f;
        const float var1 = u2 * 0.0625f - mu1 * mu1;
        const float r1 = rsqrtf(var1 + 1e-5f);
        const float h1n = tanh2_f(fmaf((pre1 - mu1) * r1, g1, be1));

        // chain A: cell0 at step t+1
        float p0 = xv, p1 = 0.f, p2 = 0.f, p3 = 0.f;
#pragma unroll
        for (int j = 0; j < 16; j += 4) {
            p0 = fmaf(M0r[j],     h0g[j],     p0);
            p1 = fmaf(M0r[j + 1], h0g[j + 1], p1);
            p2 = fmaf(M0r[j + 2], h0g[j + 2], p2);
            p3 = fmaf(M0r[j + 3], h0g[j + 3], p3);
        }
        const float pre0 = (p0 + p1) + (p2 + p3);
        float s1 = pre0, s2 = pre0 * pre0;
        RSUM16(s1);
        RSUM16(s2);
        const float mu0 = s1 * 0.0625f;
        const float var0 = s2 * 0.0625f - mu0 * mu0;
        const float r0 = rsqrtf(var0 + 1e-5f);
        const float h0n = tanh2_f(fmaf((pre0 - mu0) * r0, g0, be0));

        h1c = h1n;
        h0c = h0n;
    }
    out[b * K_ + k] = h1c;              // Z
    if (k == 0) out[256 + b] = 1.0f;    // alpha = softmax over size-1 axis
}

extern "C" void kernel_launch(void* const* d_in, const int* in_sizes, int n_in,
                              void* d_out, int out_size, void* d_ws, size_t ws_size,
                              hipStream_t stream) {
    const float* x       = (const float*)d_in[0];
    const float* sconv_w = (const float*)d_in[7];
    const float* sbn_g   = (const float*)d_in[9];
    const float* sbn_v   = (const float*)d_in[12];
    const float* dw_w    = (const float*)d_in[13];
    const float* dw_b    = (const float*)d_in[14];
    const float* wx1     = (const float*)d_in[29];
    const float* b1      = (const float*)d_in[32];
    const float* ln0_g   = (const float*)d_in[27];
    const float* ln0_b   = (const float*)d_in[28];
    const float* ln1_g   = (const float*)d_in[33];
    const float* ln1_b   = (const float*)d_in[34];
    float* ws = (float*)d_ws;
    float* out = (float*)d_out;

    P0 p;
    p.tconv_w = (const float*)d_in[1]; p.tconv_b = (const float*)d_in[2];
    p.tbn_g = (const float*)d_in[3]; p.tbn_b = (const float*)d_in[4];
    p.tbn_m = (const float*)d_in[5]; p.tbn_v = (const float*)d_in[6];
    p.sconv_b = (const float*)d_in[8];
    p.sbn_g = sbn_g; p.sbn_b = (const float*)d_in[10];
    p.sbn_m = (const float*)d_in[11]; p.sbn_v = sbn_v;
    p.pw_w = (const float*)d_in[15]; p.pw_b = (const float*)d_in[16];
    p.pbn_g = (const float*)d_in[17]; p.pbn_b = (const float*)d_in[18];
    p.pbn_m = (const float*)d_in[19]; p.pbn_v = (const float*)d_in[20];
    p.proj_w = (const float*)d_in[21]; p.proj_b = (const float*)d_in[22];
    p.wx0 = (const float*)d_in[23]; p.b0 = (const float*)d_in[26];
    p.L0 = (const float*)d_in[24]; p.ll0 = (const float*)d_in[25];
    p.L1 = (const float*)d_in[30]; p.ll1 = (const float*)d_in[31];
    p.ws = ws;

    unsigned short* w2b = (unsigned short*)(ws + OFF_W2U);
    unsigned short* w1a = (unsigned short*)(ws + OFF_W1A);

    k0a_setup<<<dim3(8), dim3(256), 0, stream>>>(p);
    k0b_repack<<<dim3(194), dim3(256), 0, stream>>>(sconv_w, sbn_g, sbn_v, w2b);
    k1z<<<dim3(1250), dim3(256), 0, stream>>>((float4*)(ws + OFF_S2R));
    k1_mfma<<<dim3(1024), dim3(256), 0, stream>>>(x, w1a, w2b, ws + OFF_S2R);
    k2_dwpw<<<dim3(320), dim3(256), 0, stream>>>(ws + OFF_S2R, ws + OFF_SB2,
                                                 dw_w, dw_b, ws + OFF_PWC,
                                                 ws + OFF_PB2, ws + OFF_WP, ws + OFF_BP,
                                                 ws + OFF_XP);
    k3_scan<<<dim3(4), dim3(64), 0, stream>>>(ws + OFF_XP, ws + OFF_M0, ws + OFF_M1,
                                              wx1, b1, ln0_g, ln0_b, ln1_g, ln1_b, out);
}

// Round 11
// 420.694 us; speedup vs baseline: 1.5734x; 1.1082x over previous
//
#include <hip/hip_runtime.h>
#include <math.h>

#define B_ 16
#define C_ 129
#define T_ 2000
#define NF_ 40
#define ED_ 64
#define K_ 16
#define TP_ 500

// workspace float offsets
#define OFF_SB2 1040     // 40     folded sconv bias
#define OFF_PWC 1088     // 3200   pw weights * pbn scale
#define OFF_PB2 4288     // 80     folded pw bias
#define OFF_WP  4368     // 1280   wx0 @ proj_w  (16x80)
#define OFF_BP  5648     // 16     wx0 @ proj_b + b0
#define OFF_M0  5664     // 256    L0@L0.T - exp(ll0) I
#define OFF_M1  5920     // 256    L1@L1.T - exp(ll1) I
#define OFF_W1A 6224     // 768    tconv A-frag prepack (3 mt x 64 lanes x 8 bf16)
#define OFF_W2U 8192     // bf16 A-frag prepack of sconv weights: 396288 ushort
#define OFF_XP  1495040  // 16*500*16  per-step cell0 input projection
#define OFF_S2R 1623040  // 1.28M  raw sconv accumulator (atomicAdd target)

typedef __attribute__((ext_vector_type(8))) short s8v;
typedef __attribute__((ext_vector_type(4))) float f4v;

#define XROW 292         // xs row stride: 256 t + 24 halo + 12 left pad

__device__ __forceinline__ float elu_f(float x) {
    return x > 0.f ? x : (__expf(x) - 1.f);
}
// tanh(x) given a2 = 2x: 1 - 2*rcp(e^{2x}+1); saturates correctly at +-inf
__device__ __forceinline__ float tanh2_f(float a2) {
    return fmaf(-2.f, __builtin_amdgcn_rcpf(__expf(a2) + 1.f), 1.f);
}
// round-half-up fp32 -> bf16
__device__ __forceinline__ unsigned bfr(float v) {
    return (__float_as_uint(v) + 0x8000u) >> 16;
}

// DPP helpers: row_ror:n ctrl = 0x120+n, rows of 16 lanes.
#define DPPF(v, ctrl) __int_as_float(__builtin_amdgcn_update_dpp( \
    0, __float_as_int(v), (ctrl), 0xF, 0xF, false))
#define DPPI(v, ctrl) __builtin_amdgcn_update_dpp(0, (v), (ctrl), 0xF, 0xF, false)

#define RSUM16(s) do {                     \
    s += DPPF(s, 0x128);                   \
    s += DPPF(s, 0x124);                   \
    s += DPPF(s, 0x122);                   \
    s += DPPF(s, 0x121);                   \
} while (0)

struct P0 {
    const float *tconv_w, *tconv_b, *tbn_g, *tbn_b, *tbn_m, *tbn_v;
    const float *sconv_b, *sbn_g, *sbn_b, *sbn_m, *sbn_v;
    const float *pw_w, *pw_b, *pbn_g, *pbn_b, *pbn_m, *pbn_v;
    const float *proj_w, *proj_b, *wx0, *b0, *L0, *ll0, *L1, *ll1;
    const float *sconv_w;
    float* ws;
};

// Merged setup: blocks [0,1250) zero s2raw; [1250,1444) repack sconv bf16
// A-frags; [1444,1452) run the table setup (all regions disjoint).
__global__ __launch_bounds__(256) void k0_all(P0 p) {
    const int tid = threadIdx.x;
    float* ws = p.ws;
    const float eps = 1e-5f;

    if (blockIdx.x < 1250) {
        const int i = blockIdx.x * 256 + tid;
        if (i < 320000)
            ((float4*)(ws + OFF_S2R))[i] = make_float4(0.f, 0.f, 0.f, 0.f);
        return;
    }
    if (blockIdx.x < 1444) {
        const int e = (blockIdx.x - 1250) * 256 + tid;
        if (e >= C_ * 3 * 2 * 64) return;
        unsigned short* w2b = (unsigned short*)(ws + OFF_W2U);
        const int c = e / 384;
        int r = e - c * 384;
        const int mt = r >> 7; r &= 127;
        const int kc = r >> 6;
        const int lane = r & 63;
        const int g = mt * 16 + (lane & 15);
        const float sinv = (g < NF_) ? p.sbn_g[g] * rsqrtf(p.sbn_v[g] + 1e-5f) : 0.f;
        unsigned short o[8];
#pragma unroll
        for (int j = 0; j < 8; ++j) {
            const int f = kc * 32 + (lane >> 4) * 8 + j;
            float v = 0.f;
            if (g < NF_ && f < NF_) v = p.sconv_w[g * (NF_ * C_) + f * C_ + c] * sinv;
            o[j] = (unsigned short)bfr(v);
        }
        unsigned short* dst = w2b + (size_t)e * 8;
#pragma unroll
        for (int j = 0; j < 8; ++j) dst[j] = o[j];
        return;
    }

    const int gtid = (blockIdx.x - 1444) * 256 + tid;
    const int stride = 8 * 256;
    // tconv A-frag prepack (bf16): A[m=f][k=tap], K=32; tap 25 = folded bias
    for (int e = gtid; e < 192; e += stride) {
        const int mt = e >> 6, L = e & 63;
        const int f = mt * 16 + (L & 15);
        float inv = 0.f, bias = 0.f;
        if (f < NF_) {
            inv = p.tbn_g[f] / sqrtf(p.tbn_v[f] + eps);
            bias = p.tconv_b[f] * inv + p.tbn_b[f] - p.tbn_m[f] * inv;
        }
        unsigned short* dst = ((unsigned short*)(ws + OFF_W1A)) + e * 8;
#pragma unroll
        for (int j = 0; j < 8; ++j) {
            const int k = (L >> 4) * 8 + j;
            float v = 0.f;
            if (f < NF_) {
                if (k < 25) v = p.tconv_w[f * 25 + k] * inv;
                else if (k == 25) v = bias;
            }
            dst[j] = (unsigned short)bfr(v);
        }
    }
    for (int f = gtid; f < NF_; f += stride) {
        const float sinv = p.sbn_g[f] / sqrtf(p.sbn_v[f] + eps);
        ws[OFF_SB2 + f] = p.sconv_b[f] * sinv + p.sbn_b[f] - p.sbn_m[f] * sinv;
    }
    for (int e = gtid; e < 3200; e += stride) {
        const int g = e / 40;
        const float pinv = p.pbn_g[g] / sqrtf(p.pbn_v[g] + eps);
        ws[OFF_PWC + e] = p.pw_w[e] * pinv;
    }
    for (int g = gtid; g < 80; g += stride) {
        const float pinv = p.pbn_g[g] / sqrtf(p.pbn_v[g] + eps);
        ws[OFF_PB2 + g] = p.pw_b[g] * pinv + p.pbn_b[g] - p.pbn_m[g] * pinv;
    }
    for (int e = gtid; e < 1280; e += stride) {
        const int k = e / 80, g = e - k * 80;
        float a = 0.f;
        for (int ee = 0; ee < ED_; ++ee)
            a = fmaf(p.wx0[k * ED_ + ee], p.proj_w[ee * 80 + g], a);
        ws[OFF_WP + e] = a;
    }
    for (int k = gtid; k < K_; k += stride) {
        float a = p.b0[k];
        for (int ee = 0; ee < ED_; ++ee)
            a = fmaf(p.wx0[k * ED_ + ee], p.proj_b[ee], a);
        ws[OFF_BP + k] = a;
    }
    for (int e = gtid; e < 256; e += stride) {
        const int k = e >> 4, j = e & 15;
        float a0 = 0.f, a1 = 0.f;
        for (int i = 0; i < 16; ++i) {
            a0 = fmaf(p.L0[k * 16 + i], p.L0[j * 16 + i], a0);
            a1 = fmaf(p.L1[k * 16 + i], p.L1[j * 16 + i], a1);
        }
        if (k == j) { a0 -= expf(p.ll0[0]); a1 -= expf(p.ll1[0]); }
        ws[OFF_M0 + e] = a0;
        ws[OFF_M1 + e] = a1;
    }
}

// Both convs on MFMA (round-9 verified, unchanged).
__global__ __launch_bounds__(256, 4) void k1_mfma(
    const float* __restrict__ x, const unsigned short* __restrict__ w1a,
    const unsigned short* __restrict__ w2b, float* __restrict__ s2raw) {
    __shared__ float xs[17 * XROW];
    __shared__ unsigned int vsI[2048];      // 4 waves x 8 rows x 64 words

    const int tid = threadIdx.x;
    const int split = blockIdx.x & 7;
    const int tile = (blockIdx.x >> 3) & 7;
    const int b = blockIdx.x >> 6;
    const int c0 = (split * C_) >> 3;
    const int c1 = ((split + 1) * C_) >> 3;
    const int cc = c1 - c0;
    const int t0 = tile << 8;
    const int w = tid >> 6;
    const int lane = tid & 63;
    const int n = lane & 15;
    const int q = lane >> 4;
    const int qh = q >> 1;
    const int q1_2 = (q & 1) * 2;
    const bool q3 = (q == 3);
    const int wb = w << 9;
    const int w64 = w << 6;
    const int ln8 = n + q * 8;

    for (int i = tid; i < 2048; i += 256) vsI[i] = 0u;
    for (int e = tid; e < cc * XROW; e += 256) {
        const int cl = e / XROW;
        const int i = e - cl * XROW;
        const int t = t0 - 12 + i;
        float v = 0.f;
        if ((unsigned)t < (unsigned)T_) v = x[(b * C_ + c0 + cl) * T_ + t];
        xs[e] = v;
    }
    __syncthreads();

    const s8v* w1a8 = (const s8v*)w1a;
    s8v wA[3];
#pragma unroll
    for (int mt = 0; mt < 3; ++mt) wA[mt] = w1a8[mt * 64 + lane];

    f4v acc[4][3];
#pragma unroll
    for (int nt = 0; nt < 4; ++nt)
#pragma unroll
        for (int mt = 0; mt < 3; ++mt) acc[nt][mt] = (f4v)0.f;

    const s8v* w2b8 = (const s8v*)w2b;
    const f4v z4 = (f4v)0.f;

    for (int cl = 0; cl < cc; ++cl) {
        const int c = c0 + cl;
        s8v af[3][2];
#pragma unroll
        for (int mt = 0; mt < 3; ++mt)
#pragma unroll
            for (int kc = 0; kc < 2; ++kc)
                af[mt][kc] = w2b8[((c * 3 + mt) * 2 + kc) * 64 + lane];

        const float* xrow = &xs[cl * XROW + w64 + ln8];

#pragma unroll
        for (int nt = 0; nt < 4; ++nt) {
            float bx[8];
#pragma unroll
            for (int j = 0; j < 8; ++j) bx[j] = xrow[nt * 16 + j];
            if (q3) bx[1] = 1.0f;
            unsigned pw_[4];
#pragma unroll
            for (int jj = 0; jj < 4; ++jj)
                pw_[jj] = bfr(bx[2 * jj]) |
                    ((__float_as_uint(bx[2 * jj + 1]) + 0x8000u) & 0xFFFF0000u);
            const s8v bh = *(const s8v*)pw_;
#pragma unroll
            for (int mt = 0; mt < 3; ++mt) {
                const f4v vT = __builtin_amdgcn_mfma_f32_16x16x32_bf16(
                    wA[mt], bh, z4, 0, 0, 0);
                const float e0 = elu_f(vT[0]);
                const float e1 = elu_f(vT[1]);
                const float e2 = elu_f(vT[2]);
                const float e3 = elu_f(vT[3]);
                const unsigned lo = bfr(e0) |
                    ((__float_as_uint(e1) + 0x8000u) & 0xFFFF0000u);
                const unsigned hi = bfr(e2) |
                    ((__float_as_uint(e3) + 0x8000u) & 0xFFFF0000u);
                const int base = wb + ((2 * mt + qh) << 6) + (n << 2) + q1_2;
                vsI[base] = lo;
                vsI[base + 1] = hi;
            }
            __builtin_amdgcn_wave_barrier();
            const s8v b0 = *(const s8v*)&vsI[wb + (q << 6) + (n << 2)];
            const s8v b1 = *(const s8v*)&vsI[wb + ((4 + q) << 6) + (n << 2)];
#pragma unroll
            for (int mt = 0; mt < 3; ++mt) {
                acc[nt][mt] = __builtin_amdgcn_mfma_f32_16x16x32_bf16(
                    af[mt][0], b0, acc[nt][mt], 0, 0, 0);
                acc[nt][mt] = __builtin_amdgcn_mfma_f32_16x16x32_bf16(
                    af[mt][1], b1, acc[nt][mt], 0, 0, 0);
            }
            __builtin_amdgcn_wave_barrier();
        }
    }

#pragma unroll
    for (int nt = 0; nt < 4; ++nt) {
        const int t = t0 + w * 64 + nt * 16 + n;
        if (t >= T_) continue;
#pragma unroll
        for (int mt = 0; mt < 3; ++mt) {
#pragma unroll
            for (int r = 0; r < 4; ++r) {
                const int g = mt * 16 + q * 4 + r;
                if (g < NF_)
                    atomicAdd(&s2raw[(b * NF_ + g) * T_ + t], acc[nt][mt][r]);
            }
        }
    }
}

// Fused dw/pw/pool/proj (verified, unchanged).
__global__ __launch_bounds__(256) void k2_dwpw(
    const float* __restrict__ s2raw, const float* __restrict__ sb2,
    const float* __restrict__ dw_w, const float* __restrict__ dw_b,
    const float* __restrict__ pwc, const float* __restrict__ pb2,
    const float* __restrict__ WP, const float* __restrict__ bp,
    float* __restrict__ xp) {
    __shared__ float st[NF_ * 114];
    __shared__ float dwo[NF_ * 100];
    __shared__ float dwwl[NF_ * 15];
    __shared__ float dwbl[NF_];
    __shared__ float pwcl[80 * 40];
    __shared__ float pb2l[80];
    __shared__ float WPl[K_ * 80];
    __shared__ float bpl[K_];
    __shared__ float po[80 * 25];
    const int tid = threadIdx.x;
    const int b = blockIdx.x / 20;
    const int tp0 = (blockIdx.x % 20) * 25;
    const int tbase = tp0 * 4 - 7;
    for (int e = tid; e < NF_ * 114; e += 256) {
        const int f = e / 114;
        const int i = e - f * 114;
        const int t = tbase + i;
        float v = 0.f;
        if ((unsigned)t < (unsigned)T_)
            v = elu_f(s2raw[(b * NF_ + f) * T_ + t] + sb2[f]);
        st[e] = v;
    }
    for (int e = tid; e < 600; e += 256) dwwl[e] = dw_w[e];
    for (int e = tid; e < 3200; e += 256) pwcl[e] = pwc[e];
    for (int e = tid; e < 1280; e += 256) WPl[e] = WP[e];
    if (tid < NF_) dwbl[tid] = dw_b[tid];
    if (tid < 80) pb2l[tid] = pb2[tid];
    if (tid < K_) bpl[tid] = bp[tid];
    __syncthreads();
    for (int e = tid; e < 4000; e += 256) {
        const int f = e / 100;
        const int tq = e - f * 100;
        float a = dwbl[f];
#pragma unroll
        for (int kk = 0; kk < 15; ++kk)
            a = fmaf(dwwl[f * 15 + kk], st[f * 114 + tq + kk], a);
        dwo[e] = a;
    }
    __syncthreads();
    for (int e = tid; e < 2000; e += 256) {
        const int g = e / 25;
        const int tp = e - g * 25;
        float sum = 0.f;
#pragma unroll
        for (int dt = 0; dt < 4; ++dt) {
            float a = pb2l[g];
            for (int f = 0; f < NF_; ++f)
                a = fmaf(pwcl[g * 40 + f], dwo[f * 100 + tp * 4 + dt], a);
            sum += elu_f(a);
        }
        po[e] = sum * 0.25f;
    }
    __syncthreads();
    for (int e = tid; e < 400; e += 256) {
        const int tp = e >> 4;
        const int k = e & 15;
        float a = bpl[k];
        for (int g = 0; g < 80; ++g)
            a = fmaf(WPl[k * 80 + g], po[g * 25 + tp], a);
        xp[(b * TP_ + tp0 + tp) * K_ + k] = a;
    }
}

// Scan, low-register formulation: 16 blocks (1 batch each), 1 wave. The 4
// 16-lane rows compute different matvecs in the same instruction stream:
// row0 = M0·h0, row1 = wx1·h0, row2 = M1·h1 (row3 idle) via a rotate-fused
// ladder (hr = ror1(hr); acc += w[j]*hr) — only 16 weight VGPRs/lane, no
// gather arrays, no spills. Three __shfl recombine rows into pre0/pre1.
// Direction-proof: weight permutation derived by running the SAME ladder on
// the lane index at init. Pipelined recurrence identical to round-10.
__global__ __launch_bounds__(64, 1) void k3_scan(
    const float* __restrict__ xp, const float* __restrict__ M0,
    const float* __restrict__ M1, const float* __restrict__ wx1,
    const float* __restrict__ b1, const float* __restrict__ ln0_g,
    const float* __restrict__ ln0_b, const float* __restrict__ ln1_g,
    const float* __restrict__ ln1_b, float* __restrict__ out) {
    const int lane = threadIdx.x;
    const int k = lane & 15;
    const int r = lane >> 4;
    const int b = blockIdx.x;

    // build this lane's permuted ladder weights (16 regs)
    float wrow[16];
    {
        int pid = k;
#pragma unroll
        for (int j = 0; j < 16; ++j) {
            pid = DPPI(pid, 0x121);
            const float w0 = M0[k * 16 + pid];
            const float w1v = wx1[k * 16 + pid];
            const float w2 = M1[k * 16 + pid];
            wrow[j] = (r == 0) ? w0 : (r == 1) ? w1v : (r == 2) ? w2 : 0.f;
        }
    }
    const float b1r = b1[k];
    const float g0 = 2.f * ln0_g[k], be0 = 2.f * ln0_b[k];
    const float g1 = 2.f * ln1_g[k], be1 = 2.f * ln1_b[k];
    const float* xpb = xp + b * TP_ * K_ + k;

    // prologue: h0_0 = tanh(LN(x_0))
    float h0c;
    {
        float x0 = xpb[0];
        float s1 = x0, s2 = x0 * x0;
        RSUM16(s1);
        RSUM16(s2);
        const float mu = s1 * 0.0625f;
        const float var = s2 * 0.0625f - mu * mu;
        const float rr = rsqrtf(var + 1e-5f);
        h0c = tanh2_f(fmaf((x0 - mu) * rr, g0, be0));
    }
    float h1c = 0.f;

    float xn[4];
    xn[1] = xpb[1 * K_];
    xn[2] = xpb[2 * K_];
    xn[3] = xpb[3 * K_];
    xn[0] = xpb[4 * K_];

    for (int t = 0; t < TP_; ++t) {
        // rotate-fused matvec: rows 0,1 ladder h0_t; row 2 ladders h1_{t-1}
        float hr = (r == 2) ? h1c : h0c;
        float a0 = 0.f, a1 = 0.f;
#pragma unroll
        for (int j = 0; j < 16; j += 2) {
            hr = DPPF(hr, 0x121);
            a0 = fmaf(wrow[j], hr, a0);
            hr = DPPF(hr, 0x121);
            a1 = fmaf(wrow[j + 1], hr, a1);
        }
        const float acc = a0 + a1;

        const int slot = (t + 1) & 3;
        const float xv = xn[slot];
        int tf = t + 5;
        if (tf > TP_ - 1) tf = TP_ - 1;
        xn[slot] = xpb[tf * K_];

        // recombine rows (acc replicated to every lane via bpermute)
        const float A0 = __shfl(acc, k, 64);        // M0·h0
        const float A1 = __shfl(acc, 16 + k, 64);   // wx1·h0
        const float A2 = __shfl(acc, 32 + k, 64);   // M1·h1
        const float pre0 = A0 + xv;
        const float pre1 = (A1 + A2) + b1r;

        float s1 = pre0, s2 = pre0 * pre0;
        float u1 = pre1, u2 = pre1 * pre1;
        RSUM16(s1);
        RSUM16(s2);
        RSUM16(u1);
        RSUM16(u2);
        const float mu0 = s1 * 0.0625f;
        const float var0 = fmaf(s2, 0.0625f, -mu0 * mu0);
        const float r0 = rsqrtf(var0 + 1e-5f);
        const float mu1 = u1 * 0.0625f;
        const float var1 = fmaf(u2, 0.0625f, -mu1 * mu1);
        const float r1 = rsqrtf(var1 + 1e-5f);
        const float h0n = tanh2_f(fmaf((pre0 - mu0) * r0, g0, be0));
        const float h1n = tanh2_f(fmaf((pre1 - mu1) * r1, g1, be1));

        h1c = h1n;
        h0c = h0n;
    }
    if (lane < 16) {
        out[b * K_ + k] = h1c;              // Z
        if (k == 0) out[256 + b] = 1.0f;    // alpha = softmax over size-1 axis
    }
}

extern "C" void kernel_launch(void* const* d_in, const int* in_sizes, int n_in,
                              void* d_out, int out_size, void* d_ws, size_t ws_size,
                              hipStream_t stream) {
    const float* x       = (const float*)d_in[0];
    const float* dw_w    = (const float*)d_in[13];
    const float* dw_b    = (const float*)d_in[14];
    const float* wx1     = (const float*)d_in[29];
    const float* b1      = (const float*)d_in[32];
    const float* ln0_g   = (const float*)d_in[27];
    const float* ln0_b   = (const float*)d_in[28];
    const float* ln1_g   = (const float*)d_in[33];
    const float* ln1_b   = (const float*)d_in[34];
    float* ws = (float*)d_ws;
    float* out = (float*)d_out;

    P0 p;
    p.tconv_w = (const float*)d_in[1]; p.tconv_b = (const float*)d_in[2];
    p.tbn_g = (const float*)d_in[3]; p.tbn_b = (const float*)d_in[4];
    p.tbn_m = (const float*)d_in[5]; p.tbn_v = (const float*)d_in[6];
    p.sconv_b = (const float*)d_in[8];
    p.sbn_g = (const float*)d_in[9]; p.sbn_b = (const float*)d_in[10];
    p.sbn_m = (const float*)d_in[11]; p.sbn_v = (const float*)d_in[12];
    p.pw_w = (const float*)d_in[15]; p.pw_b = (const float*)d_in[16];
    p.pbn_g = (const float*)d_in[17]; p.pbn_b = (const float*)d_in[18];
    p.pbn_m = (const float*)d_in[19]; p.pbn_v = (const float*)d_in[20];
    p.proj_w = (const float*)d_in[21]; p.proj_b = (const float*)d_in[22];
    p.wx0 = (const float*)d_in[23]; p.b0 = (const float*)d_in[26];
    p.L0 = (const float*)d_in[24]; p.ll0 = (const float*)d_in[25];
    p.L1 = (const float*)d_in[30]; p.ll1 = (const float*)d_in[31];
    p.sconv_w = (const float*)d_in[7];
    p.ws = ws;

    unsigned short* w2b = (unsigned short*)(ws + OFF_W2U);
    unsigned short* w1a = (unsigned short*)(ws + OFF_W1A);

    k0_all<<<dim3(1452), dim3(256), 0, stream>>>(p);
    k1_mfma<<<dim3(1024), dim3(256), 0, stream>>>(x, w1a, w2b, ws + OFF_S2R);
    k2_dwpw<<<dim3(320), dim3(256), 0, stream>>>(ws + OFF_S2R, ws + OFF_SB2,
                                                 dw_w, dw_b, ws + OFF_PWC,
                                                 ws + OFF_PB2, ws + OFF_WP, ws + OFF_BP,
                                                 ws + OFF_XP);
    k3_scan<<<dim3(16), dim3(64), 0, stream>>>(ws + OFF_XP, ws + OFF_M0, ws + OFF_M1,
                                               wx1, b1, ln0_g, ln0_b, ln1_g, ln1_b, out);
}

// Round 12
// 368.697 us; speedup vs baseline: 1.7953x; 1.1410x over previous
//
#include <hip/hip_runtime.h>
#include <math.h>

#define B_ 16
#define C_ 129
#define T_ 2000
#define NF_ 40
#define ED_ 64
#define K_ 16
#define TP_ 500

// workspace float offsets
#define OFF_SB2 1040     // 40     folded sconv bias
#define OFF_PWC 1088     // 3200   pw weights * pbn scale
#define OFF_PB2 4288     // 80     folded pw bias
#define OFF_WP  4368     // 1280   wx0 @ proj_w  (16x80)
#define OFF_BP  5648     // 16     wx0 @ proj_b + b0
#define OFF_M0  5664     // 256    L0@L0.T - exp(ll0) I
#define OFF_M1  5920     // 256    L1@L1.T - exp(ll1) I
#define OFF_W1A 6224     // 768    tconv A-frag prepack (3 mt x 64 lanes x 8 bf16)
#define OFF_W2U 8192     // bf16 A-frag prepack of sconv weights: 396288 ushort
#define OFF_XP  1495040  // 16*500*16  per-step cell0 input projection
#define OFF_S2R 1623040  // 1.28M  raw sconv accumulator (atomicAdd target)

typedef __attribute__((ext_vector_type(8))) short s8v;
typedef __attribute__((ext_vector_type(4))) float f4v;

#define XROW 292         // xs row stride: 256 t + 24 halo + 12 left pad

__device__ __forceinline__ float elu_f(float x) {
    return x > 0.f ? x : (__expf(x) - 1.f);
}
// tanh(x) given a2 = 2x: 1 - 2*rcp(e^{2x}+1); saturates correctly at +-inf
__device__ __forceinline__ float tanh2_f(float a2) {
    return fmaf(-2.f, __builtin_amdgcn_rcpf(__expf(a2) + 1.f), 1.f);
}
// round-half-up fp32 -> bf16
__device__ __forceinline__ unsigned bfr(float v) {
    return (__float_as_uint(v) + 0x8000u) >> 16;
}

// DPP helpers: row_ror:n ctrl = 0x120+n, rows of 16 lanes.
#define DPPF(v, ctrl) __int_as_float(__builtin_amdgcn_update_dpp( \
    0, __float_as_int(v), (ctrl), 0xF, 0xF, false))
#define DPPI(v, ctrl) __builtin_amdgcn_update_dpp(0, (v), (ctrl), 0xF, 0xF, false)

#define RSUM16(s) do {                     \
    s += DPPF(s, 0x128);                   \
    s += DPPF(s, 0x124);                   \
    s += DPPF(s, 0x122);                   \
    s += DPPF(s, 0x121);                   \
} while (0)

struct P0 {
    const float *tconv_w, *tconv_b, *tbn_g, *tbn_b, *tbn_m, *tbn_v;
    const float *sconv_b, *sbn_g, *sbn_b, *sbn_m, *sbn_v;
    const float *pw_w, *pw_b, *pbn_g, *pbn_b, *pbn_m, *pbn_v;
    const float *proj_w, *proj_b, *wx0, *b0, *L0, *ll0, *L1, *ll1;
    const float *sconv_w;
    float* ws;
};

// Merged setup: blocks [0,1250) zero s2raw; [1250,1444) repack sconv bf16
// A-frags; [1444,1452) run the table setup (all regions disjoint).
__global__ __launch_bounds__(256) void k0_all(P0 p) {
    const int tid = threadIdx.x;
    float* ws = p.ws;
    const float eps = 1e-5f;

    if (blockIdx.x < 1250) {
        const int i = blockIdx.x * 256 + tid;
        if (i < 320000)
            ((float4*)(ws + OFF_S2R))[i] = make_float4(0.f, 0.f, 0.f, 0.f);
        return;
    }
    if (blockIdx.x < 1444) {
        const int e = (blockIdx.x - 1250) * 256 + tid;
        if (e >= C_ * 3 * 2 * 64) return;
        unsigned short* w2b = (unsigned short*)(ws + OFF_W2U);
        const int c = e / 384;
        int r = e - c * 384;
        const int mt = r >> 7; r &= 127;
        const int kc = r >> 6;
        const int lane = r & 63;
        const int g = mt * 16 + (lane & 15);
        const float sinv = (g < NF_) ? p.sbn_g[g] * rsqrtf(p.sbn_v[g] + 1e-5f) : 0.f;
        unsigned short o[8];
#pragma unroll
        for (int j = 0; j < 8; ++j) {
            const int f = kc * 32 + (lane >> 4) * 8 + j;
            float v = 0.f;
            if (g < NF_ && f < NF_) v = p.sconv_w[g * (NF_ * C_) + f * C_ + c] * sinv;
            o[j] = (unsigned short)bfr(v);
        }
        unsigned short* dst = w2b + (size_t)e * 8;
#pragma unroll
        for (int j = 0; j < 8; ++j) dst[j] = o[j];
        return;
    }

    const int gtid = (blockIdx.x - 1444) * 256 + tid;
    const int stride = 8 * 256;
    // tconv A-frag prepack (bf16): A[m=f][k=tap], K=32; tap 25 = folded bias
    for (int e = gtid; e < 192; e += stride) {
        const int mt = e >> 6, L = e & 63;
        const int f = mt * 16 + (L & 15);
        float inv = 0.f, bias = 0.f;
        if (f < NF_) {
            inv = p.tbn_g[f] / sqrtf(p.tbn_v[f] + eps);
            bias = p.tconv_b[f] * inv + p.tbn_b[f] - p.tbn_m[f] * inv;
        }
        unsigned short* dst = ((unsigned short*)(ws + OFF_W1A)) + e * 8;
#pragma unroll
        for (int j = 0; j < 8; ++j) {
            const int k = (L >> 4) * 8 + j;
            float v = 0.f;
            if (f < NF_) {
                if (k < 25) v = p.tconv_w[f * 25 + k] * inv;
                else if (k == 25) v = bias;
            }
            dst[j] = (unsigned short)bfr(v);
        }
    }
    for (int f = gtid; f < NF_; f += stride) {
        const float sinv = p.sbn_g[f] / sqrtf(p.sbn_v[f] + eps);
        ws[OFF_SB2 + f] = p.sconv_b[f] * sinv + p.sbn_b[f] - p.sbn_m[f] * sinv;
    }
    for (int e = gtid; e < 3200; e += stride) {
        const int g = e / 40;
        const float pinv = p.pbn_g[g] / sqrtf(p.pbn_v[g] + eps);
        ws[OFF_PWC + e] = p.pw_w[e] * pinv;
    }
    for (int g = gtid; g < 80; g += stride) {
        const float pinv = p.pbn_g[g] / sqrtf(p.pbn_v[g] + eps);
        ws[OFF_PB2 + g] = p.pw_b[g] * pinv + p.pbn_b[g] - p.pbn_m[g] * pinv;
    }
    for (int e = gtid; e < 1280; e += stride) {
        const int k = e / 80, g = e - k * 80;
        float a = 0.f;
        for (int ee = 0; ee < ED_; ++ee)
            a = fmaf(p.wx0[k * ED_ + ee], p.proj_w[ee * 80 + g], a);
        ws[OFF_WP + e] = a;
    }
    for (int k = gtid; k < K_; k += stride) {
        float a = p.b0[k];
        for (int ee = 0; ee < ED_; ++ee)
            a = fmaf(p.wx0[k * ED_ + ee], p.proj_b[ee], a);
        ws[OFF_BP + k] = a;
    }
    for (int e = gtid; e < 256; e += stride) {
        const int k = e >> 4, j = e & 15;
        float a0 = 0.f, a1 = 0.f;
        for (int i = 0; i < 16; ++i) {
            a0 = fmaf(p.L0[k * 16 + i], p.L0[j * 16 + i], a0);
            a1 = fmaf(p.L1[k * 16 + i], p.L1[j * 16 + i], a1);
        }
        if (k == j) { a0 -= expf(p.ll0[0]); a1 -= expf(p.ll1[0]); }
        ws[OFF_M0 + e] = a0;
        ws[OFF_M1 + e] = a1;
    }
}

// Both convs on MFMA (round-9 verified, unchanged).
__global__ __launch_bounds__(256, 4) void k1_mfma(
    const float* __restrict__ x, const unsigned short* __restrict__ w1a,
    const unsigned short* __restrict__ w2b, float* __restrict__ s2raw) {
    __shared__ float xs[17 * XROW];
    __shared__ unsigned int vsI[2048];      // 4 waves x 8 rows x 64 words

    const int tid = threadIdx.x;
    const int split = blockIdx.x & 7;
    const int tile = (blockIdx.x >> 3) & 7;
    const int b = blockIdx.x >> 6;
    const int c0 = (split * C_) >> 3;
    const int c1 = ((split + 1) * C_) >> 3;
    const int cc = c1 - c0;
    const int t0 = tile << 8;
    const int w = tid >> 6;
    const int lane = tid & 63;
    const int n = lane & 15;
    const int q = lane >> 4;
    const int qh = q >> 1;
    const int q1_2 = (q & 1) * 2;
    const bool q3 = (q == 3);
    const int wb = w << 9;
    const int w64 = w << 6;
    const int ln8 = n + q * 8;

    for (int i = tid; i < 2048; i += 256) vsI[i] = 0u;
    for (int e = tid; e < cc * XROW; e += 256) {
        const int cl = e / XROW;
        const int i = e - cl * XROW;
        const int t = t0 - 12 + i;
        float v = 0.f;
        if ((unsigned)t < (unsigned)T_) v = x[(b * C_ + c0 + cl) * T_ + t];
        xs[e] = v;
    }
    __syncthreads();

    const s8v* w1a8 = (const s8v*)w1a;
    s8v wA[3];
#pragma unroll
    for (int mt = 0; mt < 3; ++mt) wA[mt] = w1a8[mt * 64 + lane];

    f4v acc[4][3];
#pragma unroll
    for (int nt = 0; nt < 4; ++nt)
#pragma unroll
        for (int mt = 0; mt < 3; ++mt) acc[nt][mt] = (f4v)0.f;

    const s8v* w2b8 = (const s8v*)w2b;
    const f4v z4 = (f4v)0.f;

    for (int cl = 0; cl < cc; ++cl) {
        const int c = c0 + cl;
        s8v af[3][2];
#pragma unroll
        for (int mt = 0; mt < 3; ++mt)
#pragma unroll
            for (int kc = 0; kc < 2; ++kc)
                af[mt][kc] = w2b8[((c * 3 + mt) * 2 + kc) * 64 + lane];

        const float* xrow = &xs[cl * XROW + w64 + ln8];

#pragma unroll
        for (int nt = 0; nt < 4; ++nt) {
            float bx[8];
#pragma unroll
            for (int j = 0; j < 8; ++j) bx[j] = xrow[nt * 16 + j];
            if (q3) bx[1] = 1.0f;
            unsigned pw_[4];
#pragma unroll
            for (int jj = 0; jj < 4; ++jj)
                pw_[jj] = bfr(bx[2 * jj]) |
                    ((__float_as_uint(bx[2 * jj + 1]) + 0x8000u) & 0xFFFF0000u);
            const s8v bh = *(const s8v*)pw_;
#pragma unroll
            for (int mt = 0; mt < 3; ++mt) {
                const f4v vT = __builtin_amdgcn_mfma_f32_16x16x32_bf16(
                    wA[mt], bh, z4, 0, 0, 0);
                const float e0 = elu_f(vT[0]);
                const float e1 = elu_f(vT[1]);
                const float e2 = elu_f(vT[2]);
                const float e3 = elu_f(vT[3]);
                const unsigned lo = bfr(e0) |
                    ((__float_as_uint(e1) + 0x8000u) & 0xFFFF0000u);
                const unsigned hi = bfr(e2) |
                    ((__float_as_uint(e3) + 0x8000u) & 0xFFFF0000u);
                const int base = wb + ((2 * mt + qh) << 6) + (n << 2) + q1_2;
                vsI[base] = lo;
                vsI[base + 1] = hi;
            }
            __builtin_amdgcn_wave_barrier();
            const s8v b0 = *(const s8v*)&vsI[wb + (q << 6) + (n << 2)];
            const s8v b1 = *(const s8v*)&vsI[wb + ((4 + q) << 6) + (n << 2)];
#pragma unroll
            for (int mt = 0; mt < 3; ++mt) {
                acc[nt][mt] = __builtin_amdgcn_mfma_f32_16x16x32_bf16(
                    af[mt][0], b0, acc[nt][mt], 0, 0, 0);
                acc[nt][mt] = __builtin_amdgcn_mfma_f32_16x16x32_bf16(
                    af[mt][1], b1, acc[nt][mt], 0, 0, 0);
            }
            __builtin_amdgcn_wave_barrier();
        }
    }

#pragma unroll
    for (int nt = 0; nt < 4; ++nt) {
        const int t = t0 + w * 64 + nt * 16 + n;
        if (t >= T_) continue;
#pragma unroll
        for (int mt = 0; mt < 3; ++mt) {
#pragma unroll
            for (int r = 0; r < 4; ++r) {
                const int g = mt * 16 + q * 4 + r;
                if (g < NF_)
                    atomicAdd(&s2raw[(b * NF_ + g) * T_ + t], acc[nt][mt][r]);
            }
        }
    }
}

// Fused dw/pw/pool/proj (verified, unchanged).
__global__ __launch_bounds__(256) void k2_dwpw(
    const float* __restrict__ s2raw, const float* __restrict__ sb2,
    const float* __restrict__ dw_w, const float* __restrict__ dw_b,
    const float* __restrict__ pwc, const float* __restrict__ pb2,
    const float* __restrict__ WP, const float* __restrict__ bp,
    float* __restrict__ xp) {
    __shared__ float st[NF_ * 114];
    __shared__ float dwo[NF_ * 100];
    __shared__ float dwwl[NF_ * 15];
    __shared__ float dwbl[NF_];
    __shared__ float pwcl[80 * 40];
    __shared__ float pb2l[80];
    __shared__ float WPl[K_ * 80];
    __shared__ float bpl[K_];
    __shared__ float po[80 * 25];
    const int tid = threadIdx.x;
    const int b = blockIdx.x / 20;
    const int tp0 = (blockIdx.x % 20) * 25;
    const int tbase = tp0 * 4 - 7;
    for (int e = tid; e < NF_ * 114; e += 256) {
        const int f = e / 114;
        const int i = e - f * 114;
        const int t = tbase + i;
        float v = 0.f;
        if ((unsigned)t < (unsigned)T_)
            v = elu_f(s2raw[(b * NF_ + f) * T_ + t] + sb2[f]);
        st[e] = v;
    }
    for (int e = tid; e < 600; e += 256) dwwl[e] = dw_w[e];
    for (int e = tid; e < 3200; e += 256) pwcl[e] = pwc[e];
    for (int e = tid; e < 1280; e += 256) WPl[e] = WP[e];
    if (tid < NF_) dwbl[tid] = dw_b[tid];
    if (tid < 80) pb2l[tid] = pb2[tid];
    if (tid < K_) bpl[tid] = bp[tid];
    __syncthreads();
    for (int e = tid; e < 4000; e += 256) {
        const int f = e / 100;
        const int tq = e - f * 100;
        float a = dwbl[f];
#pragma unroll
        for (int kk = 0; kk < 15; ++kk)
            a = fmaf(dwwl[f * 15 + kk], st[f * 114 + tq + kk], a);
        dwo[e] = a;
    }
    __syncthreads();
    for (int e = tid; e < 2000; e += 256) {
        const int g = e / 25;
        const int tp = e - g * 25;
        float sum = 0.f;
#pragma unroll
        for (int dt = 0; dt < 4; ++dt) {
            float a = pb2l[g];
            for (int f = 0; f < NF_; ++f)
                a = fmaf(pwcl[g * 40 + f], dwo[f * 100 + tp * 4 + dt], a);
            sum += elu_f(a);
        }
        po[e] = sum * 0.25f;
    }
    __syncthreads();
    for (int e = tid; e < 400; e += 256) {
        const int tp = e >> 4;
        const int k = e & 15;
        float a = bpl[k];
        for (int g = 0; g < 80; ++g)
            a = fmaf(WPl[k * 80 + g], po[g * 25 + tp], a);
        xp[(b * TP_ + tp0 + tp) * K_ + k] = a;
    }
}

// Scan, half-wave engine specialization: 16 blocks (1 batch), 1 wave.
// Upper half (rows 2,3): h0-engine, pre0 = M0·h0 + xv — ZERO DS ops in the
// loop-carried chain. Lower half (rows 0,1): h1-engine, pre1 = M1·h1 +
// wx1·h0recv + b1, running one step behind; the single ds_bpermute carrying
// h0 upper->lower is double-buffered (h0cur/h0pend) with a full iteration of
// slack. Two interleaved DPP rotate-ladders (independent chains fill hazard
// slots). x-ring unrolled x4 with static slots. One uniform instr stream.
#define SCAN_STEP(I, S) do {                                              \
    float vB = h0cur;                                                     \
    float a0 = 0.f, a1 = 0.f, c0 = 0.f, c1 = 0.f;                         \
    _Pragma("unroll")                                                     \
    for (int j = 0; j < 16; j += 2) {                                     \
        vA = DPPF(vA, 0x121);  a0 = fmaf(W1[j], vA, a0);                  \
        vB = DPPF(vB, 0x121);  c0 = fmaf(W2[j], vB, c0);                  \
        vA = DPPF(vA, 0x121);  a1 = fmaf(W1[j + 1], vA, a1);              \
        vB = DPPF(vB, 0x121);  c1 = fmaf(W2[j + 1], vB, c1);              \
    }                                                                     \
    const float xv = xn[S];                                               \
    int tf = (I) + 5; if (tf > TP_ - 1) tf = TP_ - 1;                     \
    xn[S] = xpb[tf * K_];                                                 \
    const float cadd = lower ? b1r : xv;                                  \
    const float pre = ((a0 + a1) + (c0 + c1)) + cadd;                     \
    float s1 = pre, s2 = pre * pre;                                       \
    RSUM16(s1);                                                           \
    RSUM16(s2);                                                           \
    const float mu = s1 * 0.0625f;                                        \
    const float var = fmaf(s2, 0.0625f, -mu * mu);                        \
    float hn = tanh2_f(fmaf((pre - mu) * rsqrtf(var + 1e-5f), gg, bb));   \
    if ((I) == 0 && lower) hn = 0.f;                                      \
    vA = hn;                                                              \
    h0cur = h0pend;                                                       \
    h0pend = __shfl(hn, 32 + k, 64);                                      \
    if ((I) == 500) h1out = vA;                                           \
} while (0)

__global__ __launch_bounds__(64, 1) void k3_scan(
    const float* __restrict__ xp, const float* __restrict__ M0,
    const float* __restrict__ M1, const float* __restrict__ wx1,
    const float* __restrict__ b1, const float* __restrict__ ln0_g,
    const float* __restrict__ ln0_b, const float* __restrict__ ln1_g,
    const float* __restrict__ ln1_b, float* __restrict__ out) {
    const int lane = threadIdx.x;
    const int k = lane & 15;
    const bool lower = lane < 32;
    const int b = blockIdx.x;

    // row-selected ladder weights, permutation matched to the ror1 ladder
    float W1[16], W2[16];
    {
        int pid = k;
#pragma unroll
        for (int j = 0; j < 16; ++j) {
            pid = DPPI(pid, 0x121);
            const float m0 = M0[k * 16 + pid];
            const float m1 = M1[k * 16 + pid];
            const float wx = wx1[k * 16 + pid];
            W1[j] = lower ? m1 : m0;
            W2[j] = lower ? wx : 0.f;
        }
    }
    const float b1r = b1[k];
    const float g0 = 2.f * ln0_g[k], be0 = 2.f * ln0_b[k];
    const float gg = lower ? 2.f * ln1_g[k] : g0;
    const float bb = lower ? 2.f * ln1_b[k] : be0;
    const float* xpb = xp + b * TP_ * K_ + k;

    // prologue: h0_0 = tanh(LN(x_0)) computed by ALL lanes (so lower's first
    // h0recv needs no bpermute)
    float h0_0;
    {
        const float x0 = xpb[0];
        float s1 = x0, s2 = x0 * x0;
        RSUM16(s1);
        RSUM16(s2);
        const float mu = s1 * 0.0625f;
        const float var = fmaf(s2, 0.0625f, -mu * mu);
        h0_0 = tanh2_f(fmaf((x0 - mu) * rsqrtf(var + 1e-5f), g0, be0));
    }
    float vA = lower ? 0.f : h0_0;   // lower: h1 state (starts 0); upper: h0
    float h0cur = 0.f;               // h0_{-1}: iter-0 lower output is forced 0
    float h0pend = h0_0;             // becomes h0cur at end of iter 0
    float h1out = 0.f;

    float xn[4];
    xn[0] = xpb[1 * K_];
    xn[1] = xpb[2 * K_];
    xn[2] = xpb[3 * K_];
    xn[3] = xpb[4 * K_];

    // iter i: upper computes h0_{i+1}; lower computes h1_{i-1}.
    // need i=0..500 (501 iters); run 504 for the x4 unroll (tail harmless).
    for (int i = 0; i < 504; i += 4) {
        SCAN_STEP(i + 0, 0);
        SCAN_STEP(i + 1, 1);
        SCAN_STEP(i + 2, 2);
        SCAN_STEP(i + 3, 3);
    }
    if (lane < 16) {
        out[b * K_ + k] = h1out;            // Z = h1_{499}
        if (k == 0) out[256 + b] = 1.0f;    // alpha = softmax over size-1 axis
    }
}

extern "C" void kernel_launch(void* const* d_in, const int* in_sizes, int n_in,
                              void* d_out, int out_size, void* d_ws, size_t ws_size,
                              hipStream_t stream) {
    const float* x       = (const float*)d_in[0];
    const float* dw_w    = (const float*)d_in[13];
    const float* dw_b    = (const float*)d_in[14];
    const float* wx1     = (const float*)d_in[29];
    const float* b1      = (const float*)d_in[32];
    const float* ln0_g   = (const float*)d_in[27];
    const float* ln0_b   = (const float*)d_in[28];
    const float* ln1_g   = (const float*)d_in[33];
    const float* ln1_b   = (const float*)d_in[34];
    float* ws = (float*)d_ws;
    float* out = (float*)d_out;

    P0 p;
    p.tconv_w = (const float*)d_in[1]; p.tconv_b = (const float*)d_in[2];
    p.tbn_g = (const float*)d_in[3]; p.tbn_b = (const float*)d_in[4];
    p.tbn_m = (const float*)d_in[5]; p.tbn_v = (const float*)d_in[6];
    p.sconv_b = (const float*)d_in[8];
    p.sbn_g = (const float*)d_in[9]; p.sbn_b = (const float*)d_in[10];
    p.sbn_m = (const float*)d_in[11]; p.sbn_v = (const float*)d_in[12];
    p.pw_w = (const float*)d_in[15]; p.pw_b = (const float*)d_in[16];
    p.pbn_g = (const float*)d_in[17]; p.pbn_b = (const float*)d_in[18];
    p.pbn_m = (const float*)d_in[19]; p.pbn_v = (const float*)d_in[20];
    p.proj_w = (const float*)d_in[21]; p.proj_b = (const float*)d_in[22];
    p.wx0 = (const float*)d_in[23]; p.b0 = (const float*)d_in[26];
    p.L0 = (const float*)d_in[24]; p.ll0 = (const float*)d_in[25];
    p.L1 = (const float*)d_in[30]; p.ll1 = (const float*)d_in[31];
    p.sconv_w = (const float*)d_in[7];
    p.ws = ws;

    unsigned short* w2b = (unsigned short*)(ws + OFF_W2U);
    unsigned short* w1a = (unsigned short*)(ws + OFF_W1A);

    k0_all<<<dim3(1452), dim3(256), 0, stream>>>(p);
    k1_mfma<<<dim3(1024), dim3(256), 0, stream>>>(x, w1a, w2b, ws + OFF_S2R);
    k2_dwpw<<<dim3(320), dim3(256), 0, stream>>>(ws + OFF_S2R, ws + OFF_SB2,
                                                 dw_w, dw_b, ws + OFF_PWC,
                                                 ws + OFF_PB2, ws + OFF_WP, ws + OFF_BP,
                                                 ws + OFF_XP);
    k3_scan<<<dim3(16), dim3(64), 0, stream>>>(ws + OFF_XP, ws + OFF_M0, ws + OFF_M1,
                                               wx1, b1, ln0_g, ln0_b, ln1_g, ln1_b, out);
}

// Round 13
// 363.420 us; speedup vs baseline: 1.8214x; 1.0145x over previous
//
#include <hip/hip_runtime.h>
#include <math.h>

#define B_ 16
#define C_ 129
#define T_ 2000
#define NF_ 40
#define ED_ 64
#define K_ 16
#define TP_ 500

// workspace float offsets
#define OFF_SB2 1040     // 40     folded sconv bias
#define OFF_PWC 1088     // 3200   pw weights * pbn scale
#define OFF_PB2 4288     // 80     folded pw bias
#define OFF_WP  4368     // 1280   wx0 @ proj_w  (16x80)
#define OFF_BP  5648     // 16     wx0 @ proj_b + b0
#define OFF_M0  5664     // 256    L0@L0.T - exp(ll0) I
#define OFF_M1  5920     // 256    L1@L1.T - exp(ll1) I
#define OFF_W1A 6224     // 768    tconv A-frag prepack (3 mt x 64 lanes x 8 bf16)
#define OFF_W2U 8192     // bf16 A-frag prepack of sconv weights: 396288 ushort
#define OFF_XP  1495040  // 16*500*16  per-step cell0 input projection
#define OFF_S2R 1623040  // 1.28M  raw sconv accumulator (atomicAdd target)

typedef __attribute__((ext_vector_type(8))) short s8v;
typedef __attribute__((ext_vector_type(4))) float f4v;

#define XROW 292         // xs row stride: 256 t + 24 halo + 12 left pad

__device__ __forceinline__ float elu_f(float x) {
    return x > 0.f ? x : (__expf(x) - 1.f);
}
// tanh(x) given a2 = 2x: 1 - 2*rcp(e^{2x}+1); saturates correctly at +-inf
__device__ __forceinline__ float tanh2_f(float a2) {
    return fmaf(-2.f, __builtin_amdgcn_rcpf(__expf(a2) + 1.f), 1.f);
}
// round-half-up fp32 -> bf16
__device__ __forceinline__ unsigned bfr(float v) {
    return (__float_as_uint(v) + 0x8000u) >> 16;
}

// DPP helpers: row_ror:n ctrl = 0x120+n, rows of 16 lanes.
#define DPPF(v, ctrl) __int_as_float(__builtin_amdgcn_update_dpp( \
    0, __float_as_int(v), (ctrl), 0xF, 0xF, false))

#define RSUM16(s) do {                     \
    s += DPPF(s, 0x128);                   \
    s += DPPF(s, 0x124);                   \
    s += DPPF(s, 0x122);                   \
    s += DPPF(s, 0x121);                   \
} while (0)

// wave-uniform broadcast of lane L's value (SGPR result)
#define RDLANE(v, L) __int_as_float(__builtin_amdgcn_readlane(__float_as_int(v), (L)))

struct P0 {
    const float *tconv_w, *tconv_b, *tbn_g, *tbn_b, *tbn_m, *tbn_v;
    const float *sconv_b, *sbn_g, *sbn_b, *sbn_m, *sbn_v;
    const float *pw_w, *pw_b, *pbn_g, *pbn_b, *pbn_m, *pbn_v;
    const float *proj_w, *proj_b, *wx0, *b0, *L0, *ll0, *L1, *ll1;
    const float *sconv_w;
    float* ws;
};

// Merged setup: blocks [0,1250) zero s2raw; [1250,1444) repack sconv bf16
// A-frags; [1444,1452) run the table setup (all regions disjoint).
__global__ __launch_bounds__(256) void k0_all(P0 p) {
    const int tid = threadIdx.x;
    float* ws = p.ws;
    const float eps = 1e-5f;

    if (blockIdx.x < 1250) {
        const int i = blockIdx.x * 256 + tid;
        if (i < 320000)
            ((float4*)(ws + OFF_S2R))[i] = make_float4(0.f, 0.f, 0.f, 0.f);
        return;
    }
    if (blockIdx.x < 1444) {
        const int e = (blockIdx.x - 1250) * 256 + tid;
        if (e >= C_ * 3 * 2 * 64) return;
        unsigned short* w2b = (unsigned short*)(ws + OFF_W2U);
        const int c = e / 384;
        int r = e - c * 384;
        const int mt = r >> 7; r &= 127;
        const int kc = r >> 6;
        const int lane = r & 63;
        const int g = mt * 16 + (lane & 15);
        const float sinv = (g < NF_) ? p.sbn_g[g] * rsqrtf(p.sbn_v[g] + 1e-5f) : 0.f;
        unsigned short o[8];
#pragma unroll
        for (int j = 0; j < 8; ++j) {
            const int f = kc * 32 + (lane >> 4) * 8 + j;
            float v = 0.f;
            if (g < NF_ && f < NF_) v = p.sconv_w[g * (NF_ * C_) + f * C_ + c] * sinv;
            o[j] = (unsigned short)bfr(v);
        }
        unsigned short* dst = w2b + (size_t)e * 8;
#pragma unroll
        for (int j = 0; j < 8; ++j) dst[j] = o[j];
        return;
    }

    const int gtid = (blockIdx.x - 1444) * 256 + tid;
    const int stride = 8 * 256;
    // tconv A-frag prepack (bf16): A[m=f][k=tap], K=32; tap 25 = folded bias
    for (int e = gtid; e < 192; e += stride) {
        const int mt = e >> 6, L = e & 63;
        const int f = mt * 16 + (L & 15);
        float inv = 0.f, bias = 0.f;
        if (f < NF_) {
            inv = p.tbn_g[f] / sqrtf(p.tbn_v[f] + eps);
            bias = p.tconv_b[f] * inv + p.tbn_b[f] - p.tbn_m[f] * inv;
        }
        unsigned short* dst = ((unsigned short*)(ws + OFF_W1A)) + e * 8;
#pragma unroll
        for (int j = 0; j < 8; ++j) {
            const int k = (L >> 4) * 8 + j;
            float v = 0.f;
            if (f < NF_) {
                if (k < 25) v = p.tconv_w[f * 25 + k] * inv;
                else if (k == 25) v = bias;
            }
            dst[j] = (unsigned short)bfr(v);
        }
    }
    for (int f = gtid; f < NF_; f += stride) {
        const float sinv = p.sbn_g[f] / sqrtf(p.sbn_v[f] + eps);
        ws[OFF_SB2 + f] = p.sconv_b[f] * sinv + p.sbn_b[f] - p.sbn_m[f] * sinv;
    }
    for (int e = gtid; e < 3200; e += stride) {
        const int g = e / 40;
        const float pinv = p.pbn_g[g] / sqrtf(p.pbn_v[g] + eps);
        ws[OFF_PWC + e] = p.pw_w[e] * pinv;
    }
    for (int g = gtid; g < 80; g += stride) {
        const float pinv = p.pbn_g[g] / sqrtf(p.pbn_v[g] + eps);
        ws[OFF_PB2 + g] = p.pw_b[g] * pinv + p.pbn_b[g] - p.pbn_m[g] * pinv;
    }
    for (int e = gtid; e < 1280; e += stride) {
        const int k = e / 80, g = e - k * 80;
        float a = 0.f;
        for (int ee = 0; ee < ED_; ++ee)
            a = fmaf(p.wx0[k * ED_ + ee], p.proj_w[ee * 80 + g], a);
        ws[OFF_WP + e] = a;
    }
    for (int k = gtid; k < K_; k += stride) {
        float a = p.b0[k];
        for (int ee = 0; ee < ED_; ++ee)
            a = fmaf(p.wx0[k * ED_ + ee], p.proj_b[ee], a);
        ws[OFF_BP + k] = a;
    }
    for (int e = gtid; e < 256; e += stride) {
        const int k = e >> 4, j = e & 15;
        float a0 = 0.f, a1 = 0.f;
        for (int i = 0; i < 16; ++i) {
            a0 = fmaf(p.L0[k * 16 + i], p.L0[j * 16 + i], a0);
            a1 = fmaf(p.L1[k * 16 + i], p.L1[j * 16 + i], a1);
        }
        if (k == j) { a0 -= expf(p.ll0[0]); a1 -= expf(p.ll1[0]); }
        ws[OFF_M0 + e] = a0;
        ws[OFF_M1 + e] = a1;
    }
}

// Both convs on MFMA (round-9 verified, unchanged).
__global__ __launch_bounds__(256, 4) void k1_mfma(
    const float* __restrict__ x, const unsigned short* __restrict__ w1a,
    const unsigned short* __restrict__ w2b, float* __restrict__ s2raw) {
    __shared__ float xs[17 * XROW];
    __shared__ unsigned int vsI[2048];      // 4 waves x 8 rows x 64 words

    const int tid = threadIdx.x;
    const int split = blockIdx.x & 7;
    const int tile = (blockIdx.x >> 3) & 7;
    const int b = blockIdx.x >> 6;
    const int c0 = (split * C_) >> 3;
    const int c1 = ((split + 1) * C_) >> 3;
    const int cc = c1 - c0;
    const int t0 = tile << 8;
    const int w = tid >> 6;
    const int lane = tid & 63;
    const int n = lane & 15;
    const int q = lane >> 4;
    const int qh = q >> 1;
    const int q1_2 = (q & 1) * 2;
    const bool q3 = (q == 3);
    const int wb = w << 9;
    const int w64 = w << 6;
    const int ln8 = n + q * 8;

    for (int i = tid; i < 2048; i += 256) vsI[i] = 0u;
    for (int e = tid; e < cc * XROW; e += 256) {
        const int cl = e / XROW;
        const int i = e - cl * XROW;
        const int t = t0 - 12 + i;
        float v = 0.f;
        if ((unsigned)t < (unsigned)T_) v = x[(b * C_ + c0 + cl) * T_ + t];
        xs[e] = v;
    }
    __syncthreads();

    const s8v* w1a8 = (const s8v*)w1a;
    s8v wA[3];
#pragma unroll
    for (int mt = 0; mt < 3; ++mt) wA[mt] = w1a8[mt * 64 + lane];

    f4v acc[4][3];
#pragma unroll
    for (int nt = 0; nt < 4; ++nt)
#pragma unroll
        for (int mt = 0; mt < 3; ++mt) acc[nt][mt] = (f4v)0.f;

    const s8v* w2b8 = (const s8v*)w2b;
    const f4v z4 = (f4v)0.f;

    for (int cl = 0; cl < cc; ++cl) {
        const int c = c0 + cl;
        s8v af[3][2];
#pragma unroll
        for (int mt = 0; mt < 3; ++mt)
#pragma unroll
            for (int kc = 0; kc < 2; ++kc)
                af[mt][kc] = w2b8[((c * 3 + mt) * 2 + kc) * 64 + lane];

        const float* xrow = &xs[cl * XROW + w64 + ln8];

#pragma unroll
        for (int nt = 0; nt < 4; ++nt) {
            float bx[8];
#pragma unroll
            for (int j = 0; j < 8; ++j) bx[j] = xrow[nt * 16 + j];
            if (q3) bx[1] = 1.0f;
            unsigned pw_[4];
#pragma unroll
            for (int jj = 0; jj < 4; ++jj)
                pw_[jj] = bfr(bx[2 * jj]) |
                    ((__float_as_uint(bx[2 * jj + 1]) + 0x8000u) & 0xFFFF0000u);
            const s8v bh = *(const s8v*)pw_;
#pragma unroll
            for (int mt = 0; mt < 3; ++mt) {
                const f4v vT = __builtin_amdgcn_mfma_f32_16x16x32_bf16(
                    wA[mt], bh, z4, 0, 0, 0);
                const float e0 = elu_f(vT[0]);
                const float e1 = elu_f(vT[1]);
                const float e2 = elu_f(vT[2]);
                const float e3 = elu_f(vT[3]);
                const unsigned lo = bfr(e0) |
                    ((__float_as_uint(e1) + 0x8000u) & 0xFFFF0000u);
                const unsigned hi = bfr(e2) |
                    ((__float_as_uint(e3) + 0x8000u) & 0xFFFF0000u);
                const int base = wb + ((2 * mt + qh) << 6) + (n << 2) + q1_2;
                vsI[base] = lo;
                vsI[base + 1] = hi;
            }
            __builtin_amdgcn_wave_barrier();
            const s8v b0 = *(const s8v*)&vsI[wb + (q << 6) + (n << 2)];
            const s8v b1 = *(const s8v*)&vsI[wb + ((4 + q) << 6) + (n << 2)];
#pragma unroll
            for (int mt = 0; mt < 3; ++mt) {
                acc[nt][mt] = __builtin_amdgcn_mfma_f32_16x16x32_bf16(
                    af[mt][0], b0, acc[nt][mt], 0, 0, 0);
                acc[nt][mt] = __builtin_amdgcn_mfma_f32_16x16x32_bf16(
                    af[mt][1], b1, acc[nt][mt], 0, 0, 0);
            }
            __builtin_amdgcn_wave_barrier();
        }
    }

#pragma unroll
    for (int nt = 0; nt < 4; ++nt) {
        const int t = t0 + w * 64 + nt * 16 + n;
        if (t >= T_) continue;
#pragma unroll
        for (int mt = 0; mt < 3; ++mt) {
#pragma unroll
            for (int r = 0; r < 4; ++r) {
                const int g = mt * 16 + q * 4 + r;
                if (g < NF_)
                    atomicAdd(&s2raw[(b * NF_ + g) * T_ + t], acc[nt][mt][r]);
            }
        }
    }
}

// Fused dw/pw/pool/proj (verified, unchanged).
__global__ __launch_bounds__(256) void k2_dwpw(
    const float* __restrict__ s2raw, const float* __restrict__ sb2,
    const float* __restrict__ dw_w, const float* __restrict__ dw_b,
    const float* __restrict__ pwc, const float* __restrict__ pb2,
    const float* __restrict__ WP, const float* __restrict__ bp,
    float* __restrict__ xp) {
    __shared__ float st[NF_ * 114];
    __shared__ float dwo[NF_ * 100];
    __shared__ float dwwl[NF_ * 15];
    __shared__ float dwbl[NF_];
    __shared__ float pwcl[80 * 40];
    __shared__ float pb2l[80];
    __shared__ float WPl[K_ * 80];
    __shared__ float bpl[K_];
    __shared__ float po[80 * 25];
    const int tid = threadIdx.x;
    const int b = blockIdx.x / 20;
    const int tp0 = (blockIdx.x % 20) * 25;
    const int tbase = tp0 * 4 - 7;
    for (int e = tid; e < NF_ * 114; e += 256) {
        const int f = e / 114;
        const int i = e - f * 114;
        const int t = tbase + i;
        float v = 0.f;
        if ((unsigned)t < (unsigned)T_)
            v = elu_f(s2raw[(b * NF_ + f) * T_ + t] + sb2[f]);
        st[e] = v;
    }
    for (int e = tid; e < 600; e += 256) dwwl[e] = dw_w[e];
    for (int e = tid; e < 3200; e += 256) pwcl[e] = pwc[e];
    for (int e = tid; e < 1280; e += 256) WPl[e] = WP[e];
    if (tid < NF_) dwbl[tid] = dw_b[tid];
    if (tid < 80) pb2l[tid] = pb2[tid];
    if (tid < K_) bpl[tid] = bp[tid];
    __syncthreads();
    for (int e = tid; e < 4000; e += 256) {
        const int f = e / 100;
        const int tq = e - f * 100;
        float a = dwbl[f];
#pragma unroll
        for (int kk = 0; kk < 15; ++kk)
            a = fmaf(dwwl[f * 15 + kk], st[f * 114 + tq + kk], a);
        dwo[e] = a;
    }
    __syncthreads();
    for (int e = tid; e < 2000; e += 256) {
        const int g = e / 25;
        const int tp = e - g * 25;
        float sum = 0.f;
#pragma unroll
        for (int dt = 0; dt < 4; ++dt) {
            float a = pb2l[g];
            for (int f = 0; f < NF_; ++f)
                a = fmaf(pwcl[g * 40 + f], dwo[f * 100 + tp * 4 + dt], a);
            sum += elu_f(a);
        }
        po[e] = sum * 0.25f;
    }
    __syncthreads();
    for (int e = tid; e < 400; e += 256) {
        const int tp = e >> 4;
        const int k = e & 15;
        float a = bpl[k];
        for (int g = 0; g < 80; ++g)
            a = fmaf(WPl[k * 80 + g], po[g * 25 + tp], a);
        xp[(b * TP_ + tp0 + tp) * K_ + k] = a;
    }
}

// Scan via readlane broadcast: 16 blocks (1 batch), 1 wave. At the top of
// each iteration, 32 INDEPENDENT v_readlane ops broadcast h0 (row 2) and h1
// (row 0) into SGPRs — no serial DPP ladder, no DS ops, no weight
// permutation. Upper half computes h0_{i+1} = tanh(LN(M0·h0_i + x_{i+1}));
// lower half computes h1_i = tanh(LN(wx1·h0_i + M1·h1_{i-1} + b1)) in the
// SAME iteration (capture-at-start makes h0_i visible). Uniform instruction
// stream; 500 iterations exactly.
#define SCAN_STEP(I, S) do {                                              \
    float sH0[16], sH1[16];                                               \
    _Pragma("unroll")                                                     \
    for (int j = 0; j < 16; ++j) {                                        \
        sH0[j] = RDLANE(vA, 32 + j);                                      \
        sH1[j] = RDLANE(vA, j);                                           \
    }                                                                     \
    float a0 = 0.f, a1 = 0.f, c0 = 0.f, c1 = 0.f;                         \
    _Pragma("unroll")                                                     \
    for (int j = 0; j < 16; j += 2) {                                     \
        a0 = fmaf(WA[j],     sH0[j],     a0);                             \
        a1 = fmaf(WA[j + 1], sH0[j + 1], a1);                             \
        c0 = fmaf(WB[j],     sH1[j],     c0);                             \
        c1 = fmaf(WB[j + 1], sH1[j + 1], c1);                             \
    }                                                                     \
    const float xv = xn[S];                                               \
    int tf = (I) + 5; if (tf > TP_ - 1) tf = TP_ - 1;                     \
    xn[S] = xpb[tf * K_];                                                 \
    const float cadd = lower ? b1r : xv;                                  \
    const float pre = ((a0 + a1) + (c0 + c1)) + cadd;                     \
    float s1 = pre, s2 = pre * pre;                                       \
    RSUM16(s1);                                                           \
    RSUM16(s2);                                                           \
    const float mu = s1 * 0.0625f;                                        \
    const float var = fmaf(s2, 0.0625f, -mu * mu);                        \
    vA = tanh2_f(fmaf((pre - mu) * rsqrtf(var + 1e-5f), gg, bb));         \
} while (0)

__global__ __launch_bounds__(64, 1) void k3_scan(
    const float* __restrict__ xp, const float* __restrict__ M0,
    const float* __restrict__ M1, const float* __restrict__ wx1,
    const float* __restrict__ b1, const float* __restrict__ ln0_g,
    const float* __restrict__ ln0_b, const float* __restrict__ ln1_g,
    const float* __restrict__ ln1_b, float* __restrict__ out) {
    const int lane = threadIdx.x;
    const int k = lane & 15;
    const bool lower = lane < 32;
    const int b = blockIdx.x;

    // direct-indexed weights: sH0[j]/sH1[j] carry exact element j, so no
    // permutation is needed (readlane formulation is layout-exact).
    float WA[16], WB[16];
#pragma unroll
    for (int j = 0; j < 16; ++j) {
        const float m0 = M0[k * 16 + j];
        const float m1 = M1[k * 16 + j];
        const float wx = wx1[k * 16 + j];
        WA[j] = lower ? wx : m0;   // coefficient on h0
        WB[j] = lower ? m1 : 0.f;  // coefficient on h1
    }
    const float b1r = b1[k];
    const float g0 = 2.f * ln0_g[k], be0 = 2.f * ln0_b[k];
    const float gg = lower ? 2.f * ln1_g[k] : g0;
    const float bb = lower ? 2.f * ln1_b[k] : be0;
    const float* xpb = xp + b * TP_ * K_ + k;

    // prologue: h0_0 = tanh(LN(x_0)) computed by all lanes
    float h0_0;
    {
        const float x0 = xpb[0];
        float s1 = x0, s2 = x0 * x0;
        RSUM16(s1);
        RSUM16(s2);
        const float mu = s1 * 0.0625f;
        const float var = fmaf(s2, 0.0625f, -mu * mu);
        h0_0 = tanh2_f(fmaf((x0 - mu) * rsqrtf(var + 1e-5f), g0, be0));
    }
    // vA: upper = h0 state (h0_0), lower = h1 state (h1_{-1} = 0)
    float vA = lower ? 0.f : h0_0;

    float xn[4];
    xn[0] = xpb[1 * K_];
    xn[1] = xpb[2 * K_];
    xn[2] = xpb[3 * K_];
    xn[3] = xpb[4 * K_];

    // iter i (0..499): upper -> h0_{i+1}; lower -> h1_i (uses h0_i, h1_{i-1})
    for (int i = 0; i < TP_; i += 4) {
        SCAN_STEP(i + 0, 0);
        SCAN_STEP(i + 1, 1);
        SCAN_STEP(i + 2, 2);
        SCAN_STEP(i + 3, 3);
    }
    if (lane < 16) {
        out[b * K_ + k] = vA;               // Z = h1_{499} (row 0 state)
        if (k == 0) out[256 + b] = 1.0f;    // alpha = softmax over size-1 axis
    }
}

extern "C" void kernel_launch(void* const* d_in, const int* in_sizes, int n_in,
                              void* d_out, int out_size, void* d_ws, size_t ws_size,
                              hipStream_t stream) {
    const float* x       = (const float*)d_in[0];
    const float* dw_w    = (const float*)d_in[13];
    const float* dw_b    = (const float*)d_in[14];
    const float* wx1     = (const float*)d_in[29];
    const float* b1      = (const float*)d_in[32];
    const float* ln0_g   = (const float*)d_in[27];
    const float* ln0_b   = (const float*)d_in[28];
    const float* ln1_g   = (const float*)d_in[33];
    const float* ln1_b   = (const float*)d_in[34];
    float* ws = (float*)d_ws;
    float* out = (float*)d_out;

    P0 p;
    p.tconv_w = (const float*)d_in[1]; p.tconv_b = (const float*)d_in[2];
    p.tbn_g = (const float*)d_in[3]; p.tbn_b = (const float*)d_in[4];
    p.tbn_m = (const float*)d_in[5]; p.tbn_v = (const float*)d_in[6];
    p.sconv_b = (const float*)d_in[8];
    p.sbn_g = (const float*)d_in[9]; p.sbn_b = (const float*)d_in[10];
    p.sbn_m = (const float*)d_in[11]; p.sbn_v = (const float*)d_in[12];
    p.pw_w = (const float*)d_in[15]; p.pw_b = (const float*)d_in[16];
    p.pbn_g = (const float*)d_in[17]; p.pbn_b = (const float*)d_in[18];
    p.pbn_m = (const float*)d_in[19]; p.pbn_v = (const float*)d_in[20];
    p.proj_w = (const float*)d_in[21]; p.proj_b = (const float*)d_in[22];
    p.wx0 = (const float*)d_in[23]; p.b0 = (const float*)d_in[26];
    p.L0 = (const float*)d_in[24]; p.ll0 = (const float*)d_in[25];
    p.L1 = (const float*)d_in[30]; p.ll1 = (const float*)d_in[31];
    p.sconv_w = (const float*)d_in[7];
    p.ws = ws;

    unsigned short* w2b = (unsigned short*)(ws + OFF_W2U);
    unsigned short* w1a = (unsigned short*)(ws + OFF_W1A);

    k0_all<<<dim3(1452), dim3(256), 0, stream>>>(p);
    k1_mfma<<<dim3(1024), dim3(256), 0, stream>>>(x, w1a, w2b, ws + OFF_S2R);
    k2_dwpw<<<dim3(320), dim3(256), 0, stream>>>(ws + OFF_S2R, ws + OFF_SB2,
                                                 dw_w, dw_b, ws + OFF_PWC,
                                                 ws + OFF_PB2, ws + OFF_WP, ws + OFF_BP,
                                                 ws + OFF_XP);
    k3_scan<<<dim3(16), dim3(64), 0, stream>>>(ws + OFF_XP, ws + OFF_M0, ws + OFF_M1,
                                               wx1, b1, ln0_g, ln0_b, ln1_g, ln1_b, out);
}